// Round 2
// baseline (725.688 us; speedup 1.0000x reference)
//
#include <hip/hip_runtime.h>
#include <hip/hip_bf16.h>

typedef __hip_bfloat16 bf16;
typedef __attribute__((ext_vector_type(8))) short short8;
typedef __attribute__((ext_vector_type(4))) float f32x4;

#define MODEL_DIM 2048
#define INNER     4096
#define NHEADS    64
#define HEAD_DIM  64
#define STATE_DIM 128
#define IN_PROJ   4416
#define NPAD      4480
#define BSZ       2
#define SEQ       4096
#define CHUNKL    64
#define NTOK      (BSZ*SEQ)      /* 8192 */
#define NCHUNK    (SEQ/CHUNKL)   /* 64 */

// ---------------- helpers ----------------
static __device__ __forceinline__ void gload_lds16(const bf16* g, bf16* l) {
  __builtin_amdgcn_global_load_lds((const __attribute__((address_space(1))) void*)g,
                                   (__attribute__((address_space(3))) void*)l, 16, 0, 0);
}

// ---------------- converts ----------------
__global__ __launch_bounds__(256) void conv_f32_to_bf16(const float* __restrict__ src,
                                                        bf16* __restrict__ dst, int n4) {
  int i = blockIdx.x * 256 + threadIdx.x;
  if (i >= n4) return;
  float4 v = *(const float4*)(src + (size_t)i * 4);
  bf16* d = dst + (size_t)i * 4;
  d[0] = __float2bfloat16(v.x); d[1] = __float2bfloat16(v.y);
  d[2] = __float2bfloat16(v.z); d[3] = __float2bfloat16(v.w);
}

__global__ __launch_bounds__(256) void conv_win_pad(const float* __restrict__ W,
                                                    bf16* __restrict__ dst) {
  int i = blockIdx.x * 256 + threadIdx.x;      // over NPAD*2048/4
  int row = (i * 4) >> 11;
  int col = (i * 4) & 2047;
  bf16* d = dst + (size_t)i * 4;
  if (row < IN_PROJ) {
    float4 v = *(const float4*)(W + (size_t)row * 2048 + col);
    d[0] = __float2bfloat16(v.x); d[1] = __float2bfloat16(v.y);
    d[2] = __float2bfloat16(v.z); d[3] = __float2bfloat16(v.w);
  } else {
    bf16 z = __float2bfloat16(0.f);
    d[0] = z; d[1] = z; d[2] = z; d[3] = z;
  }
}

// ---------------- shared GEMM main loop (A[M][K] * B[N][K]^T), 128x128 tile ----------------
#define GEMM_BODY(A, B, K)                                                              \
  __shared__ bf16 As[128 * 32];                                                         \
  __shared__ bf16 Bs[128 * 32];                                                         \
  const int t = threadIdx.x;                                                            \
  const int lane = t & 63;                                                              \
  const int wid = t >> 6;                                                               \
  const int bm = blockIdx.y * 128;                                                      \
  const int bn = blockIdx.x * 128;                                                      \
  f32x4 acc[4][4] = {};                                                                 \
  const int r0 = t >> 2, q0 = t & 3;                                                    \
  const int c1 = t + 256;                                                               \
  const int r1 = c1 >> 2, q1 = c1 & 3;                                                  \
  for (int kt = 0; kt < (K); kt += 32) {                                                \
    gload_lds16((A) + (size_t)(bm + r0) * (K) + kt + q0 * 8, As + t * 8);               \
    gload_lds16((A) + (size_t)(bm + r1) * (K) + kt + q1 * 8, As + c1 * 8);              \
    gload_lds16((B) + (size_t)(bn + r0) * (K) + kt + q0 * 8, Bs + t * 8);               \
    gload_lds16((B) + (size_t)(bn + r1) * (K) + kt + q1 * 8, Bs + c1 * 8);              \
    __syncthreads();                                                                    \
    const bf16* Ab = As + ((size_t)((wid >> 1) * 64 + (lane & 15))) * 32 + (lane >> 4) * 8; \
    const bf16* Bb = Bs + ((size_t)((wid & 1) * 64 + (lane & 15))) * 32 + (lane >> 4) * 8;  \
    short8 a[4], b[4];                                                                  \
    _Pragma("unroll") for (int i = 0; i < 4; ++i) a[i] = *(const short8*)(Ab + i * 16 * 32); \
    _Pragma("unroll") for (int i = 0; i < 4; ++i) b[i] = *(const short8*)(Bb + i * 16 * 32); \
    _Pragma("unroll") for (int mi = 0; mi < 4; ++mi)                                    \
      _Pragma("unroll") for (int ni = 0; ni < 4; ++ni)                                  \
        acc[mi][ni] = __builtin_amdgcn_mfma_f32_16x16x32_bf16(a[mi], b[ni], acc[mi][ni], 0, 0, 0); \
    __syncthreads();                                                                    \
  }

// in-proj GEMM: routed epilogue (x->bf16, B->bf16, C->bf16, dt->f32)
__global__ __launch_bounds__(256, 2)
void gemm_in(const bf16* __restrict__ A, const bf16* __restrict__ B,
             const float* __restrict__ bias, bf16* __restrict__ x_bf,
             bf16* __restrict__ B_bf, bf16* __restrict__ C_bf, float* __restrict__ dtraw) {
  GEMM_BODY(A, B, MODEL_DIM)
#pragma unroll
  for (int mi = 0; mi < 4; ++mi)
#pragma unroll
    for (int ni = 0; ni < 4; ++ni)
#pragma unroll
      for (int r = 0; r < 4; ++r) {
        int row = bm + (wid >> 1) * 64 + mi * 16 + (lane >> 4) * 4 + r;
        int col = bn + (wid & 1) * 64 + ni * 16 + (lane & 15);
        float v = acc[mi][ni][r] + ((col < IN_PROJ) ? bias[col] : 0.f);
        if (col < 4096)       x_bf[(size_t)row * 4096 + col]        = __float2bfloat16(v);
        else if (col < 4224)  B_bf[(size_t)row * 128 + (col - 4096)] = __float2bfloat16(v);
        else if (col < 4352)  C_bf[(size_t)row * 128 + (col - 4224)] = __float2bfloat16(v);
        else if (col < 4416)  dtraw[(size_t)row * 64 + (col - 4352)] = v;
      }
}

// out-proj GEMM: f32 output + bias
__global__ __launch_bounds__(256, 2)
void gemm_out(const bf16* __restrict__ A, const bf16* __restrict__ B,
              const float* __restrict__ bias, float* __restrict__ C) {
  GEMM_BODY(A, B, INNER)
#pragma unroll
  for (int mi = 0; mi < 4; ++mi)
#pragma unroll
    for (int ni = 0; ni < 4; ++ni)
#pragma unroll
      for (int r = 0; r < 4; ++r) {
        int row = bm + (wid >> 1) * 64 + mi * 16 + (lane >> 4) * 4 + r;
        int col = bn + (wid & 1) * 64 + ni * 16 + (lane & 15);
        C[(size_t)row * MODEL_DIM + col] = acc[mi][ni][r] + bias[col];
      }
}

// ---------------- prep: softplus(dt), a_dt, scale x in place ----------------
__global__ __launch_bounds__(256)
void prep_kernel(const float* __restrict__ dtraw, const float* __restrict__ A_log,
                 const float* __restrict__ dt_bias, bf16* __restrict__ x_bf,
                 float* __restrict__ a_dt) {
  __shared__ float dts[64];
  int m = blockIdx.x, t = threadIdx.x;
  if (t < 64) {
    float z = dtraw[(size_t)m * 64 + t] + dt_bias[t];
    float dt = (z > 20.f) ? z : log1pf(expf(z));
    dts[t] = dt;
    a_dt[(size_t)m * 64 + t] = -expf(A_log[t]) * dt;
  }
  __syncthreads();
#pragma unroll
  for (int i = 0; i < 2; ++i) {
    int idx = t + i * 256;                       // 512 chunks of 8 cols
    bf16* p = x_bf + (size_t)m * 4096 + idx * 8;
    short8 v = *(short8*)p;
    bf16* pv = (bf16*)&v;
    float dt = dts[idx >> 3];
#pragma unroll
    for (int j = 0; j < 8; ++j) pv[j] = __float2bfloat16(__bfloat162float(pv[j]) * dt);
    *(short8*)p = v;
  }
}

// ---------------- intra-chunk states: states[b][c][h][p][n] (bf16) ----------------
__global__ __launch_bounds__(256)
void ssd_states_kernel(const bf16* __restrict__ x_bf, const bf16* __restrict__ B_bf,
                       const float* __restrict__ a_dt, float* __restrict__ acs_g,
                       bf16* __restrict__ states_g) {
  __shared__ bf16 xT[64 * 64];      // [p][l]
  __shared__ bf16 BdT[128 * 64];    // [n][l]
  __shared__ float acs_s[64];
  int blk = blockIdx.x;             // b*4096 + c*64 + h
  int h = blk & 63, c = (blk >> 6) & 63, b = blk >> 12;
  int t = threadIdx.x, lane = t & 63, wid = t >> 6;
  int tokBase = b * SEQ + c * 64;

  if (t < 64) {
    float v = a_dt[(size_t)(tokBase + t) * 64 + h];
#pragma unroll
    for (int d = 1; d < 64; d <<= 1) { float o = __shfl_up(v, d); if (t >= d) v += o; }
    acs_s[t] = v;
    acs_g[(((size_t)(b * 64 + c)) * 64 + h) * 64 + t] = v;
  }
  __syncthreads();
  float acs63 = acs_s[63];

#pragma unroll
  for (int i = 0; i < 2; ++i) {                         // x transpose
    int chunk = t + i * 256;
    int l = chunk >> 3, p0 = (chunk & 7) * 8;
    short8 vv = *(const short8*)(x_bf + (size_t)(tokBase + l) * 4096 + h * 64 + p0);
    const bf16* pv = (const bf16*)&vv;
#pragma unroll
    for (int j = 0; j < 8; ++j) xT[(p0 + j) * 64 + l] = pv[j];
  }
#pragma unroll
  for (int i = 0; i < 4; ++i) {                         // B*decay transpose
    int chunk = t + i * 256;
    int l = chunk >> 4, n0 = (chunk & 15) * 8;
    float dec = expf(acs63 - acs_s[l]);
    short8 vv = *(const short8*)(B_bf + (size_t)(tokBase + l) * 128 + n0);
    const bf16* pv = (const bf16*)&vv;
#pragma unroll
    for (int j = 0; j < 8; ++j)
      BdT[(n0 + j) * 64 + l] = __float2bfloat16(__bfloat162float(pv[j]) * dec);
  }
  __syncthreads();

  int pBase = (wid >> 1) * 32, nBase = (wid & 1) * 64;
  f32x4 acc[2][4] = {};
#pragma unroll
  for (int ks = 0; ks < 2; ++ks) {
    short8 a[2], bb[4];
#pragma unroll
    for (int mi = 0; mi < 2; ++mi)
      a[mi] = *(const short8*)(xT + (pBase + mi * 16 + (lane & 15)) * 64 + ks * 32 + (lane >> 4) * 8);
#pragma unroll
    for (int ni = 0; ni < 4; ++ni)
      bb[ni] = *(const short8*)(BdT + (nBase + ni * 16 + (lane & 15)) * 64 + ks * 32 + (lane >> 4) * 8);
#pragma unroll
    for (int mi = 0; mi < 2; ++mi)
#pragma unroll
      for (int ni = 0; ni < 4; ++ni)
        acc[mi][ni] = __builtin_amdgcn_mfma_f32_16x16x32_bf16(a[mi], bb[ni], acc[mi][ni], 0, 0, 0);
  }
  size_t sbase = ((size_t)((b * 64 + c) * 64 + h)) * 64 * 128;
#pragma unroll
  for (int mi = 0; mi < 2; ++mi)
#pragma unroll
    for (int ni = 0; ni < 4; ++ni)
#pragma unroll
      for (int r = 0; r < 4; ++r) {
        int p = pBase + mi * 16 + (lane >> 4) * 4 + r;
        int n = nBase + ni * 16 + (lane & 15);
        states_g[sbase + (size_t)p * 128 + n] = __float2bfloat16(acc[mi][ni][r]);
      }
}

// ---------------- inter-chunk scan (in-place states -> states_prev, bf16) ----------------
__global__ __launch_bounds__(256)
void ssd_scan_kernel(bf16* __restrict__ states_g, const float* __restrict__ acs_g,
                     float* __restrict__ out_fs) {
  int blk = blockIdx.x;             // b*64 + h
  int b = blk >> 6, h = blk & 63;
  int t = threadIdx.x;
  float S[32];
#pragma unroll
  for (int i = 0; i < 32; ++i) S[i] = 0.f;
  for (int c = 0; c < 64; ++c) {
    size_t base = ((size_t)((b * 64 + c) * 64 + h)) * 8192;
    float dfac = expf(acs_g[(((size_t)(b * 64 + c)) * 64 + h) * 64 + 63]);
#pragma unroll
    for (int i = 0; i < 32; ++i) {
      int e = i * 256 + t;
      float cs = __bfloat162float(states_g[base + e]);
      states_g[base + e] = __float2bfloat16(S[i]);
      S[i] = dfac * S[i] + cs;
    }
  }
  size_t ob = (size_t)blk * 8192;
#pragma unroll
  for (int i = 0; i < 32; ++i) out_fs[ob + i * 256 + t] = S[i];
}

// ---------------- output: Y_diag + Y_off -> y written in place into x_bf ----------------
__global__ __launch_bounds__(256)
void ssd_out_kernel(bf16* __restrict__ x_bf, const bf16* __restrict__ B_bf,
                    const bf16* __restrict__ C_bf, const float* __restrict__ acs_g,
                    const bf16* __restrict__ states_g) {
  __shared__ bf16 Cs[64 * 128];     // [l][n]
  __shared__ bf16 BsMs[64 * 128];   // [s][n]; first 8KB reused as Ms[l][s]
  __shared__ bf16 xT[64 * 64];      // [p][l]
  __shared__ bf16 Sp[64 * 128];     // [p][n]
  __shared__ float acs_s[64];
  int blk = blockIdx.x;
  int h = blk & 63, c = (blk >> 6) & 63, b = blk >> 12;
  int t = threadIdx.x, lane = t & 63, wid = t >> 6;
  int tokBase = b * SEQ + c * 64;
  size_t sbase = ((size_t)((b * 64 + c) * 64 + h)) * 8192;

  if (t < 64) acs_s[t] = acs_g[(((size_t)(b * 64 + c)) * 64 + h) * 64 + t];
#pragma unroll
  for (int i = 0; i < 4; ++i) {                         // C, B natural
    int chunk = t + i * 256;
    int l = chunk >> 4, n0 = (chunk & 15) * 8;
    *(short8*)(Cs + l * 128 + n0) = *(const short8*)(C_bf + (size_t)(tokBase + l) * 128 + n0);
    *(short8*)(BsMs + l * 128 + n0) = *(const short8*)(B_bf + (size_t)(tokBase + l) * 128 + n0);
  }
#pragma unroll
  for (int i = 0; i < 2; ++i) {                         // x transpose
    int chunk = t + i * 256;
    int l = chunk >> 3, p0 = (chunk & 7) * 8;
    short8 vv = *(const short8*)(x_bf + (size_t)(tokBase + l) * 4096 + h * 64 + p0);
    const bf16* pv = (const bf16*)&vv;
#pragma unroll
    for (int j = 0; j < 8; ++j) xT[(p0 + j) * 64 + l] = pv[j];
  }
#pragma unroll
  for (int i = 0; i < 4; ++i) {                         // S_prev bf16 -> LDS
    int chunk = t + i * 256;
    *(short8*)(Sp + chunk * 8) = *(const short8*)(states_g + sbase + chunk * 8);
  }
  __syncthreads();

  // G = C * B^T  (64x64, K=128)
  int lBase = (wid >> 1) * 32, sBase = (wid & 1) * 32;
  f32x4 g[2][2] = {};
#pragma unroll
  for (int ks = 0; ks < 4; ++ks) {
    short8 a[2], bb[2];
#pragma unroll
    for (int mi = 0; mi < 2; ++mi)
      a[mi] = *(const short8*)(Cs + (lBase + mi * 16 + (lane & 15)) * 128 + ks * 32 + (lane >> 4) * 8);
#pragma unroll
    for (int ni = 0; ni < 2; ++ni)
      bb[ni] = *(const short8*)(BsMs + (sBase + ni * 16 + (lane & 15)) * 128 + ks * 32 + (lane >> 4) * 8);
#pragma unroll
    for (int mi = 0; mi < 2; ++mi)
#pragma unroll
      for (int ni = 0; ni < 2; ++ni)
        g[mi][ni] = __builtin_amdgcn_mfma_f32_16x16x32_bf16(a[mi], bb[ni], g[mi][ni], 0, 0, 0);
  }
  __syncthreads();

  bf16* Ms = BsMs;                  // overwrite B region with masked scores
#pragma unroll
  for (int mi = 0; mi < 2; ++mi)
#pragma unroll
    for (int ni = 0; ni < 2; ++ni)
#pragma unroll
      for (int r = 0; r < 4; ++r) {
        int row = lBase + mi * 16 + (lane >> 4) * 4 + r;
        int col = sBase + ni * 16 + (lane & 15);
        float lm = (row >= col) ? expf(acs_s[row] - acs_s[col]) : 0.f;
        Ms[row * 64 + col] = __float2bfloat16(g[mi][ni][r] * lm);
      }
  __syncthreads();

  // Y_diag = Ms @ x  (K=64 over s),  Y_off = Cs @ Sp^T (K=128 over n)
  int pBase = (wid & 1) * 32;
  f32x4 yd[2][2] = {}, yo[2][2] = {};
#pragma unroll
  for (int ks = 0; ks < 2; ++ks) {
    short8 a[2], bb[2];
#pragma unroll
    for (int mi = 0; mi < 2; ++mi)
      a[mi] = *(const short8*)(Ms + (lBase + mi * 16 + (lane & 15)) * 64 + ks * 32 + (lane >> 4) * 8);
#pragma unroll
    for (int ni = 0; ni < 2; ++ni)
      bb[ni] = *(const short8*)(xT + (pBase + ni * 16 + (lane & 15)) * 64 + ks * 32 + (lane >> 4) * 8);
#pragma unroll
    for (int mi = 0; mi < 2; ++mi)
#pragma unroll
      for (int ni = 0; ni < 2; ++ni)
        yd[mi][ni] = __builtin_amdgcn_mfma_f32_16x16x32_bf16(a[mi], bb[ni], yd[mi][ni], 0, 0, 0);
  }
#pragma unroll
  for (int ks = 0; ks < 4; ++ks) {
    short8 a[2], bb[2];
#pragma unroll
    for (int mi = 0; mi < 2; ++mi)
      a[mi] = *(const short8*)(Cs + (lBase + mi * 16 + (lane & 15)) * 128 + ks * 32 + (lane >> 4) * 8);
#pragma unroll
    for (int ni = 0; ni < 2; ++ni)
      bb[ni] = *(const short8*)(Sp + (pBase + ni * 16 + (lane & 15)) * 128 + ks * 32 + (lane >> 4) * 8);
#pragma unroll
    for (int mi = 0; mi < 2; ++mi)
#pragma unroll
      for (int ni = 0; ni < 2; ++ni)
        yo[mi][ni] = __builtin_amdgcn_mfma_f32_16x16x32_bf16(a[mi], bb[ni], yo[mi][ni], 0, 0, 0);
  }
  __syncthreads();                  // all xT reads done before in-place write
#pragma unroll
  for (int mi = 0; mi < 2; ++mi)
#pragma unroll
    for (int ni = 0; ni < 2; ++ni)
#pragma unroll
      for (int r = 0; r < 4; ++r) {
        int lr = lBase + mi * 16 + (lane >> 4) * 4 + r;
        int p = pBase + ni * 16 + (lane & 15);
        float val = yd[mi][ni][r] + expf(acs_s[lr]) * yo[mi][ni][r];
        x_bf[(size_t)(tokBase + lr) * 4096 + h * 64 + p] = __float2bfloat16(val);
      }
}

// ---------------- launch ----------------
extern "C" void kernel_launch(void* const* d_in, const int* in_sizes, int n_in,
                              void* d_out, int out_size, void* d_ws, size_t ws_size,
                              hipStream_t stream) {
  const float* u       = (const float*)d_in[0];
  const float* W_in    = (const float*)d_in[1];
  const float* b_in    = (const float*)d_in[2];
  const float* W_out   = (const float*)d_in[3];
  const float* b_out   = (const float*)d_in[4];
  const float* A_log   = (const float*)d_in[5];
  const float* dt_bias = (const float*)d_in[6];

  float* y_out  = (float*)d_out;
  float* fs_out = y_out + (size_t)NTOK * MODEL_DIM;

  char* ws = (char*)d_ws;
  size_t off = 0;
  auto alloc = [&](size_t bytes) { char* p = ws + off; off += (bytes + 255) & ~255ull; return p; };
  bf16*  wout_bf = (bf16*) alloc((size_t)MODEL_DIM * INNER * 2);   // 16.8 MB
  bf16*  x_bf    = (bf16*) alloc((size_t)NTOK * INNER * 2);        // 67 MB (x, then y)
  bf16*  B_bf    = (bf16*) alloc((size_t)NTOK * STATE_DIM * 2);
  bf16*  C_bf    = (bf16*) alloc((size_t)NTOK * STATE_DIM * 2);
  float* dtraw   = (float*)alloc((size_t)NTOK * NHEADS * 4);
  float* a_dt    = (float*)alloc((size_t)NTOK * NHEADS * 4);
  float* acs     = (float*)alloc((size_t)BSZ * NCHUNK * NHEADS * 64 * 4);
  // region Q: states (bf16, 134 MB) aliased with {u_bf, win_bf} (dead after gemm_in)
  char*  Q       = alloc((size_t)BSZ * NCHUNK * NHEADS * 64 * 128 * 2);
  bf16*  states  = (bf16*)Q;
  bf16*  u_bf    = (bf16*)Q;
  bf16*  win_bf  = u_bf + (size_t)NTOK * MODEL_DIM;
  (void)ws_size; (void)off; (void)in_sizes; (void)n_in; (void)out_size;

  conv_f32_to_bf16<<<dim3(16384), dim3(256), 0, stream>>>(u, u_bf, NTOK * MODEL_DIM / 4);
  conv_win_pad<<<dim3(8960), dim3(256), 0, stream>>>(W_in, win_bf);
  conv_f32_to_bf16<<<dim3(8192), dim3(256), 0, stream>>>(W_out, wout_bf, MODEL_DIM * INNER / 4);

  gemm_in<<<dim3(NPAD / 128, NTOK / 128), dim3(256), 0, stream>>>(
      u_bf, win_bf, b_in, x_bf, B_bf, C_bf, dtraw);

  prep_kernel<<<dim3(NTOK), dim3(256), 0, stream>>>(dtraw, A_log, dt_bias, x_bf, a_dt);

  ssd_states_kernel<<<dim3(BSZ * NCHUNK * NHEADS), dim3(256), 0, stream>>>(
      x_bf, B_bf, a_dt, acs, states);

  ssd_scan_kernel<<<dim3(BSZ * NHEADS), dim3(256), 0, stream>>>(states, acs, fs_out);

  ssd_out_kernel<<<dim3(BSZ * NCHUNK * NHEADS), dim3(256), 0, stream>>>(
      x_bf, B_bf, C_bf, acs, states);

  gemm_out<<<dim3(MODEL_DIM / 128, NTOK / 128), dim3(256), 0, stream>>>(
      x_bf, wout_bf, b_out, y_out);
}

// Round 3
// 681.608 us; speedup vs baseline: 1.0647x; 1.0647x over previous
//
#include <hip/hip_runtime.h>
#include <hip/hip_bf16.h>

typedef __hip_bfloat16 bf16;
typedef __attribute__((ext_vector_type(8))) short short8;
typedef __attribute__((ext_vector_type(4))) float f32x4;

#define MODEL_DIM 2048
#define INNER     4096
#define NHEADS    64
#define HEAD_DIM  64
#define STATE_DIM 128
#define IN_PROJ   4416
#define NPAD      4608        /* padded to 18*256 for the 256-tile GEMM */
#define BSZ       2
#define SEQ       4096
#define CHUNKL    64
#define NTOK      (BSZ*SEQ)      /* 8192 */
#define NCHUNK    (SEQ/CHUNKL)   /* 64 */

#define WAITV4() asm volatile("s_waitcnt vmcnt(4)" ::: "memory")
#define WAITV0() asm volatile("s_waitcnt vmcnt(0)" ::: "memory")
#define BAR()    __builtin_amdgcn_s_barrier()

// ---------------- helpers ----------------
static __device__ __forceinline__ void gload_lds16(const bf16* g, bf16* l) {
  __builtin_amdgcn_global_load_lds((const __attribute__((address_space(1))) void*)g,
                                   (__attribute__((address_space(3))) void*)l, 16, 0, 0);
}

// stage one 16KB half-tile (128 rows x 64 cols bf16) with inverse st_16x32 swizzle on
// the global source; LDS dest is linear (wave base + lane*16).
static __device__ __forceinline__ void stage_half(const bf16* __restrict__ P, int K,
                                                  int blockRow, int kt,
                                                  char* region /*32KB matrix region*/,
                                                  int half, int t) {
  int o = half * 16384 + ((t >> 6) << 11) + ((t & 63) << 4);
#pragma unroll
  for (int s = 0; s < 2; ++s) {
    int oo = o + s * 1024;
    int lb = oo ^ (((oo >> 9) & 1) << 5);      // involution: logical byte for this slot
    int row = lb >> 7, colb = lb & 127;
    gload_lds16(P + (size_t)(blockRow + row) * K + kt + (colb >> 1), (bf16*)(region + oo));
  }
}

// swizzled ds_read address for a fragment at logical (row, kbyte)
static __device__ __forceinline__ const short8* frag_ptr(const char* region, int row, int kbyte) {
  int lb = (row << 7) + kbyte;
  int phys = lb ^ (((lb >> 9) & 1) << 5);
  return (const short8*)(region + phys);
}

// ---------------- 256x256 / BK=64 / 8-wave / 4-phase counted-vmcnt GEMM core ----------------
static __device__ __forceinline__ void gemm256_core(
    const bf16* __restrict__ Ag, const bf16* __restrict__ Bg,
    int K, int NT, int bm, int bn, char* lds, f32x4 (&acc)[8][4]) {
  const int t = threadIdx.x;
  const int lane = t & 63;
  const int wid = t >> 6;
  const int wm = wid >> 2, wn = wid & 3;
  const int kb = (lane >> 4) << 4;             // (lane>>4)*16 bytes

  // prologue: tile0 A+B, tile1 B  (oldest 8 loads = tile0)
  stage_half(Ag, K, bm, 0,  lds,               0, t);
  stage_half(Ag, K, bm, 0,  lds,               1, t);
  stage_half(Bg, K, bn, 0,  lds + 32768,       0, t);
  stage_half(Bg, K, bn, 0,  lds + 32768,       1, t);
  stage_half(Bg, K, bn, 64, lds + 65536 + 32768, 0, t);
  stage_half(Bg, K, bn, 64, lds + 65536 + 32768, 1, t);
  WAITV4();
  BAR();

  int cur = 0;
  for (int tt = 0; tt < NT; ++tt) {
    const char* cA = lds + cur * 65536;
    const char* cB = cA + 32768;
    char* oA = lds + (cur ^ 1) * 65536;        // A of tile t+1 -> other buffer
    char* sB = lds + cur * 65536 + 32768;      // B of tile t+2 -> current buffer
    const int kt = tt * 64;

    short8 a0[4][2], a1[4][2], b0[2][2], b1[2][2];

    // ---- phase 0: read a(m0-3), b(n0-1); stage A.h0(t+1); MFMA Q(m0-3, n0-1)
#pragma unroll
    for (int mf = 0; mf < 4; ++mf)
#pragma unroll
      for (int ks = 0; ks < 2; ++ks)
        a0[mf][ks] = *frag_ptr(cA, wm * 128 + mf * 16 + (lane & 15), ks * 64 + kb);
#pragma unroll
    for (int nf = 0; nf < 2; ++nf)
#pragma unroll
      for (int ks = 0; ks < 2; ++ks)
        b0[nf][ks] = *frag_ptr(cB, wn * 64 + nf * 16 + (lane & 15), ks * 64 + kb);
    if (tt + 1 < NT) stage_half(Ag, K, bm, kt + 64, oA, 0, t);
    BAR();
    __builtin_amdgcn_s_setprio(1);
#pragma unroll
    for (int mf = 0; mf < 4; ++mf)
#pragma unroll
      for (int nf = 0; nf < 2; ++nf)
#pragma unroll
        for (int ks = 0; ks < 2; ++ks)
          acc[mf][nf] = __builtin_amdgcn_mfma_f32_16x16x32_bf16(a0[mf][ks], b0[nf][ks], acc[mf][nf], 0, 0, 0);
    __builtin_amdgcn_s_setprio(0);
    BAR();

    // ---- phase 1: read b(n2-3); stage A.h1(t+1); MFMA Q(m0-3, n2-3)
#pragma unroll
    for (int nf = 0; nf < 2; ++nf)
#pragma unroll
      for (int ks = 0; ks < 2; ++ks)
        b1[nf][ks] = *frag_ptr(cB, wn * 64 + (2 + nf) * 16 + (lane & 15), ks * 64 + kb);
    if (tt + 1 < NT) stage_half(Ag, K, bm, kt + 64, oA, 1, t);
    BAR();
    __builtin_amdgcn_s_setprio(1);
#pragma unroll
    for (int mf = 0; mf < 4; ++mf)
#pragma unroll
      for (int nf = 0; nf < 2; ++nf)
#pragma unroll
        for (int ks = 0; ks < 2; ++ks)
          acc[mf][2 + nf] = __builtin_amdgcn_mfma_f32_16x16x32_bf16(a0[mf][ks], b1[nf][ks], acc[mf][2 + nf], 0, 0, 0);
    __builtin_amdgcn_s_setprio(0);
    BAR();

    // ---- phase 2: read a(m4-7); stage B.h0(t+2); MFMA Q(m4-7, n2-3)
#pragma unroll
    for (int mf = 0; mf < 4; ++mf)
#pragma unroll
      for (int ks = 0; ks < 2; ++ks)
        a1[mf][ks] = *frag_ptr(cA, wm * 128 + (4 + mf) * 16 + (lane & 15), ks * 64 + kb);
    if (tt + 2 < NT) stage_half(Bg, K, bn, kt + 128, sB, 0, t);
    BAR();
    __builtin_amdgcn_s_setprio(1);
#pragma unroll
    for (int mf = 0; mf < 4; ++mf)
#pragma unroll
      for (int nf = 0; nf < 2; ++nf)
#pragma unroll
        for (int ks = 0; ks < 2; ++ks)
          acc[4 + mf][2 + nf] = __builtin_amdgcn_mfma_f32_16x16x32_bf16(a1[mf][ks], b1[nf][ks], acc[4 + mf][2 + nf], 0, 0, 0);
    __builtin_amdgcn_s_setprio(0);
    BAR();

    // ---- phase 3: stage B.h1(t+2); MFMA Q(m4-7, n0-1); tile-boundary counted vmcnt
    if (tt + 2 < NT) stage_half(Bg, K, bn, kt + 128, sB, 1, t);
    BAR();
    __builtin_amdgcn_s_setprio(1);
#pragma unroll
    for (int mf = 0; mf < 4; ++mf)
#pragma unroll
      for (int nf = 0; nf < 2; ++nf)
#pragma unroll
        for (int ks = 0; ks < 2; ++ks)
          acc[4 + mf][nf] = __builtin_amdgcn_mfma_f32_16x16x32_bf16(a1[mf][ks], b0[nf][ks], acc[4 + mf][nf], 0, 0, 0);
    __builtin_amdgcn_s_setprio(0);
    if (tt < NT - 2)       { WAITV4(); BAR(); }
    else if (tt == NT - 2) { WAITV0(); BAR(); }
    else                   { BAR(); }
    cur ^= 1;
  }
}

// in-proj GEMM: routed epilogue (x->bf16, B->bf16, C->bf16, dt->f32)
__global__ __launch_bounds__(512, 2)
void gemm_in256(const bf16* __restrict__ A, const bf16* __restrict__ Bw,
                const float* __restrict__ bias, bf16* __restrict__ x_bf,
                bf16* __restrict__ B_bf, bf16* __restrict__ C_bf, float* __restrict__ dtraw) {
  __shared__ char lds[131072];
  int nwg = gridDim.x, bid = blockIdx.x;
  int cpx = nwg >> 3;
  int sb = (bid & 7) * cpx + (bid >> 3);       // bijective: nwg % 8 == 0
  int bx = sb % (NPAD / 256), by = sb / (NPAD / 256);
  int bm = by * 256, bn = bx * 256;
  f32x4 acc[8][4] = {};
  gemm256_core(A, Bw, MODEL_DIM, MODEL_DIM / 64, bm, bn, lds, acc);
  const int lane = threadIdx.x & 63, wid = threadIdx.x >> 6;
  const int wm = wid >> 2, wn = wid & 3;
#pragma unroll
  for (int mf = 0; mf < 8; ++mf)
#pragma unroll
    for (int nf = 0; nf < 4; ++nf)
#pragma unroll
      for (int r = 0; r < 4; ++r) {
        int row = bm + wm * 128 + mf * 16 + (lane >> 4) * 4 + r;
        int col = bn + wn * 64 + nf * 16 + (lane & 15);
        float v = acc[mf][nf][r] + ((col < IN_PROJ) ? bias[col] : 0.f);
        if (col < 4096)       x_bf[(size_t)row * 4096 + col]         = __float2bfloat16(v);
        else if (col < 4224)  B_bf[(size_t)row * 128 + (col - 4096)] = __float2bfloat16(v);
        else if (col < 4352)  C_bf[(size_t)row * 128 + (col - 4224)] = __float2bfloat16(v);
        else if (col < 4416)  dtraw[(size_t)row * 64 + (col - 4352)] = v;
      }
}

// out-proj GEMM: f32 output + bias
__global__ __launch_bounds__(512, 2)
void gemm_out256(const bf16* __restrict__ A, const bf16* __restrict__ Bw,
                 const float* __restrict__ bias, float* __restrict__ C) {
  __shared__ char lds[131072];
  int nwg = gridDim.x, bid = blockIdx.x;
  int cpx = nwg >> 3;
  int sb = (bid & 7) * cpx + (bid >> 3);
  int bx = sb % (MODEL_DIM / 256), by = sb / (MODEL_DIM / 256);
  int bm = by * 256, bn = bx * 256;
  f32x4 acc[8][4] = {};
  gemm256_core(A, Bw, INNER, INNER / 64, bm, bn, lds, acc);
  const int lane = threadIdx.x & 63, wid = threadIdx.x >> 6;
  const int wm = wid >> 2, wn = wid & 3;
#pragma unroll
  for (int mf = 0; mf < 8; ++mf)
#pragma unroll
    for (int nf = 0; nf < 4; ++nf)
#pragma unroll
      for (int r = 0; r < 4; ++r) {
        int row = bm + wm * 128 + mf * 16 + (lane >> 4) * 4 + r;
        int col = bn + wn * 64 + nf * 16 + (lane & 15);
        C[(size_t)row * MODEL_DIM + col] = acc[mf][nf][r] + bias[col];
      }
}

// ---------------- converts ----------------
__global__ __launch_bounds__(256) void conv_f32_to_bf16(const float* __restrict__ src,
                                                        bf16* __restrict__ dst, int n4) {
  int i = blockIdx.x * 256 + threadIdx.x;
  if (i >= n4) return;
  float4 v = *(const float4*)(src + (size_t)i * 4);
  bf16* d = dst + (size_t)i * 4;
  d[0] = __float2bfloat16(v.x); d[1] = __float2bfloat16(v.y);
  d[2] = __float2bfloat16(v.z); d[3] = __float2bfloat16(v.w);
}

__global__ __launch_bounds__(256) void conv_win_pad(const float* __restrict__ W,
                                                    bf16* __restrict__ dst) {
  int i = blockIdx.x * 256 + threadIdx.x;      // over NPAD*2048/4
  int row = (i * 4) >> 11;
  int col = (i * 4) & 2047;
  bf16* d = dst + (size_t)i * 4;
  if (row < IN_PROJ) {
    float4 v = *(const float4*)(W + (size_t)row * 2048 + col);
    d[0] = __float2bfloat16(v.x); d[1] = __float2bfloat16(v.y);
    d[2] = __float2bfloat16(v.z); d[3] = __float2bfloat16(v.w);
  } else {
    bf16 z = __float2bfloat16(0.f);
    d[0] = z; d[1] = z; d[2] = z; d[3] = z;
  }
}

// ---------------- prep: dt tables only (no x rewrite) ----------------
__global__ __launch_bounds__(256)
void prep_small(const float* __restrict__ dtraw, const float* __restrict__ A_log,
                const float* __restrict__ dt_bias, float* __restrict__ dts,
                float* __restrict__ a_dt) {
  int i = blockIdx.x * 256 + threadIdx.x;      // NTOK*64
  int h = i & 63;
  float z = dtraw[i] + dt_bias[h];
  float dt = (z > 20.f) ? z : log1pf(expf(z));
  dts[i] = dt;
  a_dt[i] = -expf(A_log[h]) * dt;
}

// ---------------- intra-chunk states: states[b][c][h][p][n] (bf16) ----------------
__global__ __launch_bounds__(256)
void ssd_states_kernel(const bf16* __restrict__ x_bf, const bf16* __restrict__ B_bf,
                       const float* __restrict__ dts, const float* __restrict__ a_dt,
                       float* __restrict__ acs_g, bf16* __restrict__ states_g) {
  __shared__ bf16 xT[64 * 64];      // [p][l]
  __shared__ bf16 BdT[128 * 64];    // [n][l]
  __shared__ float acs_s[64];
  int blk = blockIdx.x;             // b*4096 + c*64 + h
  int h = blk & 63, c = (blk >> 6) & 63, b = blk >> 12;
  int t = threadIdx.x, lane = t & 63, wid = t >> 6;
  int tokBase = b * SEQ + c * 64;

  if (t < 64) {
    float v = a_dt[(size_t)(tokBase + t) * 64 + h];
#pragma unroll
    for (int d = 1; d < 64; d <<= 1) { float o = __shfl_up(v, d); if (t >= d) v += o; }
    acs_s[t] = v;
    acs_g[(((size_t)(b * 64 + c)) * 64 + h) * 64 + t] = v;
  }
  __syncthreads();
  float acs63 = acs_s[63];

#pragma unroll
  for (int i = 0; i < 2; ++i) {                         // x transpose (+ dt scale)
    int chunk = t + i * 256;
    int l = chunk >> 3, p0 = (chunk & 7) * 8;
    float dtv = dts[(size_t)(tokBase + l) * 64 + h];
    short8 vv = *(const short8*)(x_bf + (size_t)(tokBase + l) * 4096 + h * 64 + p0);
    const bf16* pv = (const bf16*)&vv;
#pragma unroll
    for (int j = 0; j < 8; ++j)
      xT[(p0 + j) * 64 + l] = __float2bfloat16(__bfloat162float(pv[j]) * dtv);
  }
#pragma unroll
  for (int i = 0; i < 4; ++i) {                         // B*decay transpose
    int chunk = t + i * 256;
    int l = chunk >> 4, n0 = (chunk & 15) * 8;
    float dec = expf(acs63 - acs_s[l]);
    short8 vv = *(const short8*)(B_bf + (size_t)(tokBase + l) * 128 + n0);
    const bf16* pv = (const bf16*)&vv;
#pragma unroll
    for (int j = 0; j < 8; ++j)
      BdT[(n0 + j) * 64 + l] = __float2bfloat16(__bfloat162float(pv[j]) * dec);
  }
  __syncthreads();

  int pBase = (wid >> 1) * 32, nBase = (wid & 1) * 64;
  f32x4 acc[2][4] = {};
#pragma unroll
  for (int ks = 0; ks < 2; ++ks) {
    short8 a[2], bb[4];
#pragma unroll
    for (int mi = 0; mi < 2; ++mi)
      a[mi] = *(const short8*)(xT + (pBase + mi * 16 + (lane & 15)) * 64 + ks * 32 + (lane >> 4) * 8);
#pragma unroll
    for (int ni = 0; ni < 4; ++ni)
      bb[ni] = *(const short8*)(BdT + (nBase + ni * 16 + (lane & 15)) * 64 + ks * 32 + (lane >> 4) * 8);
#pragma unroll
    for (int mi = 0; mi < 2; ++mi)
#pragma unroll
      for (int ni = 0; ni < 4; ++ni)
        acc[mi][ni] = __builtin_amdgcn_mfma_f32_16x16x32_bf16(a[mi], bb[ni], acc[mi][ni], 0, 0, 0);
  }
  size_t sbase = ((size_t)((b * 64 + c) * 64 + h)) * 64 * 128;
#pragma unroll
  for (int mi = 0; mi < 2; ++mi)
#pragma unroll
    for (int ni = 0; ni < 4; ++ni)
#pragma unroll
      for (int r = 0; r < 4; ++r) {
        int p = pBase + mi * 16 + (lane >> 4) * 4 + r;
        int n = nBase + ni * 16 + (lane & 15);
        states_g[sbase + (size_t)p * 128 + n] = __float2bfloat16(acc[mi][ni][r]);
      }
}

// ---------------- inter-chunk scan (in-place states -> states_prev, bf16) ----------------
__global__ __launch_bounds__(256)
void ssd_scan_kernel(bf16* __restrict__ states_g, const float* __restrict__ acs_g,
                     float* __restrict__ out_fs) {
  int blk = blockIdx.x;             // b*64 + h
  int b = blk >> 6, h = blk & 63;
  int t = threadIdx.x;
  float S[32];
#pragma unroll
  for (int i = 0; i < 32; ++i) S[i] = 0.f;
  for (int c = 0; c < 64; ++c) {
    size_t base = ((size_t)((b * 64 + c) * 64 + h)) * 8192;
    float dfac = expf(acs_g[(((size_t)(b * 64 + c)) * 64 + h) * 64 + 63]);
#pragma unroll
    for (int i = 0; i < 32; ++i) {
      int e = i * 256 + t;
      float cs = __bfloat162float(states_g[base + e]);
      states_g[base + e] = __float2bfloat16(S[i]);
      S[i] = dfac * S[i] + cs;
    }
  }
  size_t ob = (size_t)blk * 8192;
#pragma unroll
  for (int i = 0; i < 32; ++i) out_fs[ob + i * 256 + t] = S[i];
}

// ---------------- output: Y_diag + Y_off -> y written in place into x_bf ----------------
__global__ __launch_bounds__(256)
void ssd_out_kernel(bf16* __restrict__ x_bf, const bf16* __restrict__ B_bf,
                    const bf16* __restrict__ C_bf, const float* __restrict__ dts,
                    const float* __restrict__ acs_g, const bf16* __restrict__ states_g) {
  __shared__ bf16 Cs[64 * 128];     // [l][n]
  __shared__ bf16 BsMs[64 * 128];   // [s][n]; first 8KB reused as Ms[l][s]
  __shared__ bf16 xT[64 * 64];      // [p][l]
  __shared__ bf16 Sp[64 * 128];     // [p][n]
  __shared__ float acs_s[64];
  int blk = blockIdx.x;
  int h = blk & 63, c = (blk >> 6) & 63, b = blk >> 12;
  int t = threadIdx.x, lane = t & 63, wid = t >> 6;
  int tokBase = b * SEQ + c * 64;
  size_t sbase = ((size_t)((b * 64 + c) * 64 + h)) * 8192;

  if (t < 64) acs_s[t] = acs_g[(((size_t)(b * 64 + c)) * 64 + h) * 64 + t];
#pragma unroll
  for (int i = 0; i < 4; ++i) {                         // C, B natural
    int chunk = t + i * 256;
    int l = chunk >> 4, n0 = (chunk & 15) * 8;
    *(short8*)(Cs + l * 128 + n0) = *(const short8*)(C_bf + (size_t)(tokBase + l) * 128 + n0);
    *(short8*)(BsMs + l * 128 + n0) = *(const short8*)(B_bf + (size_t)(tokBase + l) * 128 + n0);
  }
#pragma unroll
  for (int i = 0; i < 2; ++i) {                         // x transpose (+ dt scale)
    int chunk = t + i * 256;
    int l = chunk >> 3, p0 = (chunk & 7) * 8;
    float dtv = dts[(size_t)(tokBase + l) * 64 + h];
    short8 vv = *(const short8*)(x_bf + (size_t)(tokBase + l) * 4096 + h * 64 + p0);
    const bf16* pv = (const bf16*)&vv;
#pragma unroll
    for (int j = 0; j < 8; ++j)
      xT[(p0 + j) * 64 + l] = __float2bfloat16(__bfloat162float(pv[j]) * dtv);
  }
#pragma unroll
  for (int i = 0; i < 4; ++i) {                         // S_prev bf16 -> LDS
    int chunk = t + i * 256;
    *(short8*)(Sp + chunk * 8) = *(const short8*)(states_g + sbase + chunk * 8);
  }
  __syncthreads();

  // G = C * B^T  (64x64, K=128)
  int lBase = (wid >> 1) * 32, sBase = (wid & 1) * 32;
  f32x4 g[2][2] = {};
#pragma unroll
  for (int ks = 0; ks < 4; ++ks) {
    short8 a[2], bb[2];
#pragma unroll
    for (int mi = 0; mi < 2; ++mi)
      a[mi] = *(const short8*)(Cs + (lBase + mi * 16 + (lane & 15)) * 128 + ks * 32 + (lane >> 4) * 8);
#pragma unroll
    for (int ni = 0; ni < 2; ++ni)
      bb[ni] = *(const short8*)(BsMs + (sBase + ni * 16 + (lane & 15)) * 128 + ks * 32 + (lane >> 4) * 8);
#pragma unroll
    for (int mi = 0; mi < 2; ++mi)
#pragma unroll
      for (int ni = 0; ni < 2; ++ni)
        g[mi][ni] = __builtin_amdgcn_mfma_f32_16x16x32_bf16(a[mi], bb[ni], g[mi][ni], 0, 0, 0);
  }
  __syncthreads();

  bf16* Ms = BsMs;                  // overwrite B region with masked scores
#pragma unroll
  for (int mi = 0; mi < 2; ++mi)
#pragma unroll
    for (int ni = 0; ni < 2; ++ni)
#pragma unroll
      for (int r = 0; r < 4; ++r) {
        int row = lBase + mi * 16 + (lane >> 4) * 4 + r;
        int col = sBase + ni * 16 + (lane & 15);
        float lm = (row >= col) ? expf(acs_s[row] - acs_s[col]) : 0.f;
        Ms[row * 64 + col] = __float2bfloat16(g[mi][ni][r] * lm);
      }
  __syncthreads();

  // Y_diag = Ms @ x  (K=64 over s),  Y_off = Cs @ Sp^T (K=128 over n)
  int pBase = (wid & 1) * 32;
  f32x4 yd[2][2] = {}, yo[2][2] = {};
#pragma unroll
  for (int ks = 0; ks < 2; ++ks) {
    short8 a[2], bb[2];
#pragma unroll
    for (int mi = 0; mi < 2; ++mi)
      a[mi] = *(const short8*)(Ms + (lBase + mi * 16 + (lane & 15)) * 64 + ks * 32 + (lane >> 4) * 8);
#pragma unroll
    for (int ni = 0; ni < 2; ++ni)
      bb[ni] = *(const short8*)(xT + (pBase + ni * 16 + (lane & 15)) * 64 + ks * 32 + (lane >> 4) * 8);
#pragma unroll
    for (int mi = 0; mi < 2; ++mi)
#pragma unroll
      for (int ni = 0; ni < 2; ++ni)
        yd[mi][ni] = __builtin_amdgcn_mfma_f32_16x16x32_bf16(a[mi], bb[ni], yd[mi][ni], 0, 0, 0);
  }
#pragma unroll
  for (int ks = 0; ks < 4; ++ks) {
    short8 a[2], bb[2];
#pragma unroll
    for (int mi = 0; mi < 2; ++mi)
      a[mi] = *(const short8*)(Cs + (lBase + mi * 16 + (lane & 15)) * 128 + ks * 32 + (lane >> 4) * 8);
#pragma unroll
    for (int ni = 0; ni < 2; ++ni)
      bb[ni] = *(const short8*)(Sp + (pBase + ni * 16 + (lane & 15)) * 128 + ks * 32 + (lane >> 4) * 8);
#pragma unroll
    for (int mi = 0; mi < 2; ++mi)
#pragma unroll
      for (int ni = 0; ni < 2; ++ni)
        yo[mi][ni] = __builtin_amdgcn_mfma_f32_16x16x32_bf16(a[mi], bb[ni], yo[mi][ni], 0, 0, 0);
  }
  __syncthreads();                  // all xT reads done before in-place write
#pragma unroll
  for (int mi = 0; mi < 2; ++mi)
#pragma unroll
    for (int ni = 0; ni < 2; ++ni)
#pragma unroll
      for (int r = 0; r < 4; ++r) {
        int lr = lBase + mi * 16 + (lane >> 4) * 4 + r;
        int p = pBase + ni * 16 + (lane & 15);
        float val = yd[mi][ni][r] + expf(acs_s[lr]) * yo[mi][ni][r];
        x_bf[(size_t)(tokBase + lr) * 4096 + h * 64 + p] = __float2bfloat16(val);
      }
}

// ---------------- launch ----------------
extern "C" void kernel_launch(void* const* d_in, const int* in_sizes, int n_in,
                              void* d_out, int out_size, void* d_ws, size_t ws_size,
                              hipStream_t stream) {
  const float* u       = (const float*)d_in[0];
  const float* W_in    = (const float*)d_in[1];
  const float* b_in    = (const float*)d_in[2];
  const float* W_out   = (const float*)d_in[3];
  const float* b_out   = (const float*)d_in[4];
  const float* A_log   = (const float*)d_in[5];
  const float* dt_bias = (const float*)d_in[6];

  float* y_out  = (float*)d_out;
  float* fs_out = y_out + (size_t)NTOK * MODEL_DIM;

  char* ws = (char*)d_ws;
  size_t off = 0;
  auto alloc = [&](size_t bytes) { char* p = ws + off; off += (bytes + 255) & ~255ull; return p; };
  bf16*  wout_bf = (bf16*) alloc((size_t)MODEL_DIM * INNER * 2);   // 16.8 MB
  bf16*  x_bf    = (bf16*) alloc((size_t)NTOK * INNER * 2);        // 67 MB (x, then y)
  bf16*  B_bf    = (bf16*) alloc((size_t)NTOK * STATE_DIM * 2);
  bf16*  C_bf    = (bf16*) alloc((size_t)NTOK * STATE_DIM * 2);
  float* dtraw   = (float*)alloc((size_t)NTOK * NHEADS * 4);
  float* dts     = (float*)alloc((size_t)NTOK * NHEADS * 4);
  float* a_dt    = (float*)alloc((size_t)NTOK * NHEADS * 4);
  float* acs     = (float*)alloc((size_t)BSZ * NCHUNK * NHEADS * 64 * 4);
  // region Q: states (bf16, 134 MB) aliased with {u_bf, win_bf} (dead after gemm_in)
  char*  Q       = alloc((size_t)BSZ * NCHUNK * NHEADS * 64 * 128 * 2);
  bf16*  states  = (bf16*)Q;
  bf16*  u_bf    = (bf16*)Q;
  bf16*  win_bf  = u_bf + (size_t)NTOK * MODEL_DIM;
  (void)ws_size; (void)off; (void)in_sizes; (void)n_in; (void)out_size;

  conv_f32_to_bf16<<<dim3(16384), dim3(256), 0, stream>>>(u, u_bf, NTOK * MODEL_DIM / 4);
  conv_win_pad<<<dim3(NPAD * MODEL_DIM / 1024), dim3(256), 0, stream>>>(W_in, win_bf);
  conv_f32_to_bf16<<<dim3(8192), dim3(256), 0, stream>>>(W_out, wout_bf, MODEL_DIM * INNER / 4);

  gemm_in256<<<dim3((NPAD / 256) * (NTOK / 256)), dim3(512), 0, stream>>>(
      u_bf, win_bf, b_in, x_bf, B_bf, C_bf, dtraw);

  prep_small<<<dim3(NTOK * NHEADS / 256), dim3(256), 0, stream>>>(dtraw, A_log, dt_bias, dts, a_dt);

  ssd_states_kernel<<<dim3(BSZ * NCHUNK * NHEADS), dim3(256), 0, stream>>>(
      x_bf, B_bf, dts, a_dt, acs, states);

  ssd_scan_kernel<<<dim3(BSZ * NHEADS), dim3(256), 0, stream>>>(states, acs, fs_out);

  ssd_out_kernel<<<dim3(BSZ * NCHUNK * NHEADS), dim3(256), 0, stream>>>(
      x_bf, B_bf, C_bf, dts, acs, states);

  gemm_out256<<<dim3((MODEL_DIM / 256) * (NTOK / 256)), dim3(512), 0, stream>>>(
      x_bf, wout_bf, b_out, y_out);
}

// Round 4
// 643.269 us; speedup vs baseline: 1.1281x; 1.0596x over previous
//
#include <hip/hip_runtime.h>
#include <hip/hip_bf16.h>

typedef __hip_bfloat16 bf16;
typedef __attribute__((ext_vector_type(8))) short short8;
typedef __attribute__((ext_vector_type(4))) float f32x4;

#define MODEL_DIM 2048
#define INNER     4096
#define NHEADS    64
#define HEAD_DIM  64
#define STATE_DIM 128
#define IN_PROJ   4416
#define NPAD      4608        /* padded to 18*256 for the 256-tile GEMM */
#define BSZ       2
#define SEQ       4096
#define CHUNKL    64
#define NTOK      (BSZ*SEQ)      /* 8192 */
#define NCHUNK    (SEQ/CHUNKL)   /* 64 */

#define WAITV8() asm volatile("s_waitcnt vmcnt(8)" ::: "memory")
#define WAITV0() asm volatile("s_waitcnt vmcnt(0)" ::: "memory")
#define BAR()    __builtin_amdgcn_s_barrier()
#define WAITLGKM() do { asm volatile("s_waitcnt lgkmcnt(0)" ::: "memory"); \
                        __builtin_amdgcn_sched_barrier(0); } while (0)

// swizzle: XOR the 16B-slot index (bits 4-6) with row&7 (bits 7-9). Involution.
#define SWZ(x) ((x) ^ ((((x) >> 7) & 7) << 4))

// ---------------- helpers ----------------
static __device__ __forceinline__ void gload_lds16(const bf16* g, bf16* l) {
  __builtin_amdgcn_global_load_lds((const __attribute__((address_space(1))) void*)g,
                                   (__attribute__((address_space(3))) void*)l, 16, 0, 0);
}

static __device__ __forceinline__ unsigned lds_u32(const void* p) {
  return (unsigned)(unsigned long long)(const __attribute__((address_space(3))) char*)p;
}

static __device__ __forceinline__ short8 ds_read128(unsigned addr) {
  short8 r;
  asm volatile("ds_read_b128 %0, %1" : "=v"(r) : "v"(addr));
  return r;
}

// stage one 16KB half-tile (128 rows x 64 cols bf16); LDS dest linear, global source
// pre-permuted by the inverse (= same) swizzle.
static __device__ __forceinline__ void stage_half(const bf16* __restrict__ P, int K,
                                                  int blockRow, int kt,
                                                  char* region /*32KB matrix region*/,
                                                  int half, int t) {
  int o = half * 16384 + ((t >> 6) << 11) + ((t & 63) << 4);
#pragma unroll
  for (int s = 0; s < 2; ++s) {
    int oo = o + s * 1024;
    int lb = SWZ(oo);                          // logical byte this physical slot holds
    int row = lb >> 7, colb = lb & 127;
    gload_lds16(P + (size_t)(blockRow + row) * K + kt + (colb >> 1), (bf16*)(region + oo));
  }
}

// ---------------- 256x256 / BK=64 / 8-wave / 4-phase counted-vmcnt GEMM core ----------------
static __device__ __forceinline__ void gemm256_core(
    const bf16* __restrict__ Ag, const bf16* __restrict__ Bg,
    int K, int NT, int bm, int bn, char* lds, f32x4 (&acc)[8][4]) {
  const int t = threadIdx.x;
  const int lane = t & 63;
  const int wid = t >> 6;
  const int wm = wid >> 2, wn = wid & 3;
  const int lane15 = lane & 15;
  const unsigned x16 = (unsigned)(lane & 7) << 4;       // read-side swizzle XOR
  const unsigned kb0 = (unsigned)(lane >> 4) << 4;      // 0,16,32,48
  const unsigned ldsBase = lds_u32(lds);
  const unsigned aRow0 = (unsigned)(wm * 128 + lane15) * 128;
  const unsigned bRow0 = (unsigned)(wn * 64 + lane15) * 128;

  // prologue: tile0 A+B, then tile1 B, tile1 A  (matches steady-state issue order)
  stage_half(Ag, K, bm, 0,  lds,                 0, t);
  stage_half(Ag, K, bm, 0,  lds,                 1, t);
  stage_half(Bg, K, bn, 0,  lds + 32768,         0, t);
  stage_half(Bg, K, bn, 0,  lds + 32768,         1, t);
  stage_half(Bg, K, bn, 64, lds + 65536 + 32768, 0, t);
  stage_half(Bg, K, bn, 64, lds + 65536 + 32768, 1, t);
  stage_half(Ag, K, bm, 64, lds + 65536,         0, t);
  stage_half(Ag, K, bm, 64, lds + 65536,         1, t);
  WAITV8();
  BAR();

  int cur = 0;
  for (int tt = 0; tt < NT; ++tt) {
    const int kt = tt * 64;
    const unsigned aB = ldsBase + (unsigned)(cur << 16);
    const unsigned bB = aB + 32768;
    char* cAw = lds + (cur << 16);
    char* cBw = cAw + 32768;
    short8 a0[4][2], a1[4][2], b0[2][2], b1[2][2];

    // ---- phase 0: read a(m0-3), b(n0-1); MFMA Q(m0-3, n0-1)
#pragma unroll
    for (int mf = 0; mf < 4; ++mf)
#pragma unroll
      for (int ks = 0; ks < 2; ++ks)
        a0[mf][ks] = ds_read128(aB + aRow0 + mf * 2048 + (((unsigned)(ks * 64) + kb0) ^ x16));
#pragma unroll
    for (int nf = 0; nf < 2; ++nf)
#pragma unroll
      for (int ks = 0; ks < 2; ++ks)
        b0[nf][ks] = ds_read128(bB + bRow0 + nf * 2048 + (((unsigned)(ks * 64) + kb0) ^ x16));
    BAR();
    WAITLGKM();
    __builtin_amdgcn_s_setprio(1);
#pragma unroll
    for (int mf = 0; mf < 4; ++mf)
#pragma unroll
      for (int nf = 0; nf < 2; ++nf)
#pragma unroll
        for (int ks = 0; ks < 2; ++ks)
          acc[mf][nf] = __builtin_amdgcn_mfma_f32_16x16x32_bf16(a0[mf][ks], b0[nf][ks], acc[mf][nf], 0, 0, 0);
    __builtin_amdgcn_s_setprio(0);
    BAR();

    // ---- phase 1: read b(n2-3); MFMA Q(m0-3, n2-3)
#pragma unroll
    for (int nf = 0; nf < 2; ++nf)
#pragma unroll
      for (int ks = 0; ks < 2; ++ks)
        b1[nf][ks] = ds_read128(bB + bRow0 + (2 + nf) * 2048 + (((unsigned)(ks * 64) + kb0) ^ x16));
    BAR();
    WAITLGKM();
    __builtin_amdgcn_s_setprio(1);
#pragma unroll
    for (int mf = 0; mf < 4; ++mf)
#pragma unroll
      for (int nf = 0; nf < 2; ++nf)
#pragma unroll
        for (int ks = 0; ks < 2; ++ks)
          acc[mf][2 + nf] = __builtin_amdgcn_mfma_f32_16x16x32_bf16(a0[mf][ks], b1[nf][ks], acc[mf][2 + nf], 0, 0, 0);
    __builtin_amdgcn_s_setprio(0);
    BAR();

    // ---- phase 2: read a(m4-7); stage B(t+2) both halves; MFMA Q(m4-7, n2-3)
#pragma unroll
    for (int mf = 0; mf < 4; ++mf)
#pragma unroll
      for (int ks = 0; ks < 2; ++ks)
        a1[mf][ks] = ds_read128(aB + aRow0 + (4 + mf) * 2048 + (((unsigned)(ks * 64) + kb0) ^ x16));
    if (tt + 2 < NT) {
      stage_half(Bg, K, bn, kt + 128, cBw, 0, t);
      stage_half(Bg, K, bn, kt + 128, cBw, 1, t);
    }
    BAR();
    WAITLGKM();
    __builtin_amdgcn_s_setprio(1);
#pragma unroll
    for (int mf = 0; mf < 4; ++mf)
#pragma unroll
      for (int nf = 0; nf < 2; ++nf)
#pragma unroll
        for (int ks = 0; ks < 2; ++ks)
          acc[4 + mf][2 + nf] = __builtin_amdgcn_mfma_f32_16x16x32_bf16(a1[mf][ks], b1[nf][ks], acc[4 + mf][2 + nf], 0, 0, 0);
    __builtin_amdgcn_s_setprio(0);
    BAR();

    // ---- phase 3: stage A(t+2) both halves; MFMA Q(m4-7, n0-1); boundary counted vmcnt
    if (tt + 2 < NT) {
      stage_half(Ag, K, bm, kt + 128, cAw, 0, t);
      stage_half(Ag, K, bm, kt + 128, cAw, 1, t);
    }
    BAR();
    __builtin_amdgcn_s_setprio(1);
#pragma unroll
    for (int mf = 0; mf < 4; ++mf)
#pragma unroll
      for (int nf = 0; nf < 2; ++nf)
#pragma unroll
        for (int ks = 0; ks < 2; ++ks)
          acc[4 + mf][nf] = __builtin_amdgcn_mfma_f32_16x16x32_bf16(a1[mf][ks], b0[nf][ks], acc[4 + mf][nf], 0, 0, 0);
    __builtin_amdgcn_s_setprio(0);
    if (tt < NT - 2)       WAITV8();   // drains A(t+1)/B(t+1); leaves B(t+2),A(t+2) in flight
    else if (tt == NT - 2) WAITV0();
    BAR();
    cur ^= 1;
  }
}

// in-proj GEMM: routed epilogue (x->bf16, B->bf16, C->bf16, dt->f32)
__global__ __launch_bounds__(512, 2)
void gemm_in256(const bf16* __restrict__ A, const bf16* __restrict__ Bw,
                const float* __restrict__ bias, bf16* __restrict__ x_bf,
                bf16* __restrict__ B_bf, bf16* __restrict__ C_bf, float* __restrict__ dtraw) {
  __shared__ char lds[131072];
  int nwg = gridDim.x, bid = blockIdx.x;
  int cpx = nwg >> 3;
  int sb = (bid & 7) * cpx + (bid >> 3);       // bijective: nwg % 8 == 0
  int bx = sb % (NPAD / 256), by = sb / (NPAD / 256);
  int bm = by * 256, bn = bx * 256;
  f32x4 acc[8][4] = {};
  gemm256_core(A, Bw, MODEL_DIM, MODEL_DIM / 64, bm, bn, lds, acc);
  const int lane = threadIdx.x & 63, wid = threadIdx.x >> 6;
  const int wm = wid >> 2, wn = wid & 3;
#pragma unroll
  for (int mf = 0; mf < 8; ++mf)
#pragma unroll
    for (int nf = 0; nf < 4; ++nf)
#pragma unroll
      for (int r = 0; r < 4; ++r) {
        int row = bm + wm * 128 + mf * 16 + (lane >> 4) * 4 + r;
        int col = bn + wn * 64 + nf * 16 + (lane & 15);
        float v = acc[mf][nf][r] + ((col < IN_PROJ) ? bias[col] : 0.f);
        if (col < 4096)       x_bf[(size_t)row * 4096 + col]         = __float2bfloat16(v);
        else if (col < 4224)  B_bf[(size_t)row * 128 + (col - 4096)] = __float2bfloat16(v);
        else if (col < 4352)  C_bf[(size_t)row * 128 + (col - 4224)] = __float2bfloat16(v);
        else if (col < 4416)  dtraw[(size_t)row * 64 + (col - 4352)] = v;
      }
}

// out-proj GEMM: f32 output + bias
__global__ __launch_bounds__(512, 2)
void gemm_out256(const bf16* __restrict__ A, const bf16* __restrict__ Bw,
                 const float* __restrict__ bias, float* __restrict__ C) {
  __shared__ char lds[131072];
  int nwg = gridDim.x, bid = blockIdx.x;
  int cpx = nwg >> 3;
  int sb = (bid & 7) * cpx + (bid >> 3);
  int bx = sb % (MODEL_DIM / 256), by = sb / (MODEL_DIM / 256);
  int bm = by * 256, bn = bx * 256;
  f32x4 acc[8][4] = {};
  gemm256_core(A, Bw, INNER, INNER / 64, bm, bn, lds, acc);
  const int lane = threadIdx.x & 63, wid = threadIdx.x >> 6;
  const int wm = wid >> 2, wn = wid & 3;
#pragma unroll
  for (int mf = 0; mf < 8; ++mf)
#pragma unroll
    for (int nf = 0; nf < 4; ++nf)
#pragma unroll
      for (int r = 0; r < 4; ++r) {
        int row = bm + wm * 128 + mf * 16 + (lane >> 4) * 4 + r;
        int col = bn + wn * 64 + nf * 16 + (lane & 15);
        C[(size_t)row * MODEL_DIM + col] = acc[mf][nf][r] + bias[col];
      }
}

// ---------------- converts ----------------
__global__ __launch_bounds__(256) void conv_f32_to_bf16(const float* __restrict__ src,
                                                        bf16* __restrict__ dst, int n4) {
  int i = blockIdx.x * 256 + threadIdx.x;
  if (i >= n4) return;
  float4 v = *(const float4*)(src + (size_t)i * 4);
  bf16* d = dst + (size_t)i * 4;
  d[0] = __float2bfloat16(v.x); d[1] = __float2bfloat16(v.y);
  d[2] = __float2bfloat16(v.z); d[3] = __float2bfloat16(v.w);
}

__global__ __launch_bounds__(256) void conv_win_pad(const float* __restrict__ W,
                                                    bf16* __restrict__ dst) {
  int i = blockIdx.x * 256 + threadIdx.x;      // over NPAD*2048/4
  int row = (i * 4) >> 11;
  int col = (i * 4) & 2047;
  bf16* d = dst + (size_t)i * 4;
  if (row < IN_PROJ) {
    float4 v = *(const float4*)(W + (size_t)row * 2048 + col);
    d[0] = __float2bfloat16(v.x); d[1] = __float2bfloat16(v.y);
    d[2] = __float2bfloat16(v.z); d[3] = __float2bfloat16(v.w);
  } else {
    bf16 z = __float2bfloat16(0.f);
    d[0] = z; d[1] = z; d[2] = z; d[3] = z;
  }
}

// ---------------- prep: dt tables only ----------------
__global__ __launch_bounds__(256)
void prep_small(const float* __restrict__ dtraw, const float* __restrict__ A_log,
                const float* __restrict__ dt_bias, float* __restrict__ dts,
                float* __restrict__ a_dt) {
  int i = blockIdx.x * 256 + threadIdx.x;      // NTOK*64
  int h = i & 63;
  float z = dtraw[i] + dt_bias[h];
  float dt = (z > 20.f) ? z : log1pf(expf(z));
  dts[i] = dt;
  a_dt[i] = -expf(A_log[h]) * dt;
}

// ---------------- intra-chunk states: states[b][c][h][p][n] (bf16) ----------------
__global__ __launch_bounds__(256)
void ssd_states_kernel(const bf16* __restrict__ x_bf, const bf16* __restrict__ B_bf,
                       const float* __restrict__ dts, const float* __restrict__ a_dt,
                       float* __restrict__ acs_g, bf16* __restrict__ states_g) {
  __shared__ bf16 xT[64 * 64];      // [p][l]
  __shared__ bf16 BdT[128 * 64];    // [n][l]
  __shared__ float acs_s[64];
  int blk = blockIdx.x;             // b*4096 + c*64 + h
  int h = blk & 63, c = (blk >> 6) & 63, b = blk >> 12;
  int t = threadIdx.x, lane = t & 63, wid = t >> 6;
  int tokBase = b * SEQ + c * 64;

  if (t < 64) {
    float v = a_dt[(size_t)(tokBase + t) * 64 + h];
#pragma unroll
    for (int d = 1; d < 64; d <<= 1) { float o = __shfl_up(v, d); if (t >= d) v += o; }
    acs_s[t] = v;
    acs_g[(((size_t)(b * 64 + c)) * 64 + h) * 64 + t] = v;
  }
  __syncthreads();
  float acs63 = acs_s[63];

#pragma unroll
  for (int i = 0; i < 2; ++i) {                         // x transpose (+ dt scale)
    int chunk = t + i * 256;
    int l = chunk >> 3, p0 = (chunk & 7) * 8;
    float dtv = dts[(size_t)(tokBase + l) * 64 + h];
    short8 vv = *(const short8*)(x_bf + (size_t)(tokBase + l) * 4096 + h * 64 + p0);
    const bf16* pv = (const bf16*)&vv;
#pragma unroll
    for (int j = 0; j < 8; ++j)
      xT[(p0 + j) * 64 + l] = __float2bfloat16(__bfloat162float(pv[j]) * dtv);
  }
#pragma unroll
  for (int i = 0; i < 4; ++i) {                         // B*decay transpose
    int chunk = t + i * 256;
    int l = chunk >> 4, n0 = (chunk & 15) * 8;
    float dec = expf(acs63 - acs_s[l]);
    short8 vv = *(const short8*)(B_bf + (size_t)(tokBase + l) * 128 + n0);
    const bf16* pv = (const bf16*)&vv;
#pragma unroll
    for (int j = 0; j < 8; ++j)
      BdT[(n0 + j) * 64 + l] = __float2bfloat16(__bfloat162float(pv[j]) * dec);
  }
  __syncthreads();

  int pBase = (wid >> 1) * 32, nBase = (wid & 1) * 64;
  f32x4 acc[2][4] = {};
#pragma unroll
  for (int ks = 0; ks < 2; ++ks) {
    short8 a[2], bb[4];
#pragma unroll
    for (int mi = 0; mi < 2; ++mi)
      a[mi] = *(const short8*)(xT + (pBase + mi * 16 + (lane & 15)) * 64 + ks * 32 + (lane >> 4) * 8);
#pragma unroll
    for (int ni = 0; ni < 4; ++ni)
      bb[ni] = *(const short8*)(BdT + (nBase + ni * 16 + (lane & 15)) * 64 + ks * 32 + (lane >> 4) * 8);
#pragma unroll
    for (int mi = 0; mi < 2; ++mi)
#pragma unroll
      for (int ni = 0; ni < 4; ++ni)
        acc[mi][ni] = __builtin_amdgcn_mfma_f32_16x16x32_bf16(a[mi], bb[ni], acc[mi][ni], 0, 0, 0);
  }
  size_t sbase = ((size_t)((b * 64 + c) * 64 + h)) * 64 * 128;
#pragma unroll
  for (int mi = 0; mi < 2; ++mi)
#pragma unroll
    for (int ni = 0; ni < 4; ++ni)
#pragma unroll
      for (int r = 0; r < 4; ++r) {
        int p = pBase + mi * 16 + (lane >> 4) * 4 + r;
        int n = nBase + ni * 16 + (lane & 15);
        states_g[sbase + (size_t)p * 128 + n] = __float2bfloat16(acc[mi][ni][r]);
      }
}

// ---------------- inter-chunk scan (in-place states -> states_prev, bf16) ----------------
__global__ __launch_bounds__(256)
void ssd_scan_kernel(bf16* __restrict__ states_g, const float* __restrict__ acs_g,
                     float* __restrict__ out_fs) {
  int blk = blockIdx.x;             // (b*64 + h)*4 + q
  int q = blk & 3, bh = blk >> 2;
  int b = bh >> 6, h = bh & 63;
  int t = threadIdx.x;
  int eb = q * 2048 + t;
  float S[8];
#pragma unroll
  for (int i = 0; i < 8; ++i) S[i] = 0.f;
  for (int c = 0; c < 64; ++c) {
    size_t base = ((size_t)((b * 64 + c) * 64 + h)) * 8192;
    float dfac = expf(acs_g[(((size_t)(b * 64 + c)) * 64 + h) * 64 + 63]);
#pragma unroll
    for (int i = 0; i < 8; ++i) {
      int e = eb + i * 256;
      float cs = __bfloat162float(states_g[base + e]);
      states_g[base + e] = __float2bfloat16(S[i]);
      S[i] = dfac * S[i] + cs;
    }
  }
  size_t ob = (size_t)bh * 8192;
#pragma unroll
  for (int i = 0; i < 8; ++i) out_fs[ob + eb + i * 256] = S[i];
}

// ---------------- output: Y_diag + Y_off -> y written in place into x_bf ----------------
__global__ __launch_bounds__(256)
void ssd_out_kernel(bf16* __restrict__ x_bf, const bf16* __restrict__ B_bf,
                    const bf16* __restrict__ C_bf, const float* __restrict__ dts,
                    const float* __restrict__ acs_g, const bf16* __restrict__ states_g) {
  __shared__ bf16 Cs[64 * 128];     // [l][n]
  __shared__ bf16 BsMs[64 * 128];   // [s][n]; first 8KB reused as Ms[l][s]
  __shared__ bf16 xT[64 * 64];      // [p][l]
  __shared__ bf16 Sp[64 * 128];     // [p][n]
  __shared__ float acs_s[64];
  int blk = blockIdx.x;
  int h = blk & 63, c = (blk >> 6) & 63, b = blk >> 12;
  int t = threadIdx.x, lane = t & 63, wid = t >> 6;
  int tokBase = b * SEQ + c * 64;
  size_t sbase = ((size_t)((b * 64 + c) * 64 + h)) * 8192;

  if (t < 64) acs_s[t] = acs_g[(((size_t)(b * 64 + c)) * 64 + h) * 64 + t];
#pragma unroll
  for (int i = 0; i < 4; ++i) {                         // C, B natural
    int chunk = t + i * 256;
    int l = chunk >> 4, n0 = (chunk & 15) * 8;
    *(short8*)(Cs + l * 128 + n0) = *(const short8*)(C_bf + (size_t)(tokBase + l) * 128 + n0);
    *(short8*)(BsMs + l * 128 + n0) = *(const short8*)(B_bf + (size_t)(tokBase + l) * 128 + n0);
  }
#pragma unroll
  for (int i = 0; i < 2; ++i) {                         // x transpose (+ dt scale)
    int chunk = t + i * 256;
    int l = chunk >> 3, p0 = (chunk & 7) * 8;
    float dtv = dts[(size_t)(tokBase + l) * 64 + h];
    short8 vv = *(const short8*)(x_bf + (size_t)(tokBase + l) * 4096 + h * 64 + p0);
    const bf16* pv = (const bf16*)&vv;
#pragma unroll
    for (int j = 0; j < 8; ++j)
      xT[(p0 + j) * 64 + l] = __float2bfloat16(__bfloat162float(pv[j]) * dtv);
  }
#pragma unroll
  for (int i = 0; i < 4; ++i) {                         // S_prev bf16 -> LDS
    int chunk = t + i * 256;
    *(short8*)(Sp + chunk * 8) = *(const short8*)(states_g + sbase + chunk * 8);
  }
  __syncthreads();

  // G = C * B^T  (64x64, K=128)
  int lBase = (wid >> 1) * 32, sBase = (wid & 1) * 32;
  f32x4 g[2][2] = {};
#pragma unroll
  for (int ks = 0; ks < 4; ++ks) {
    short8 a[2], bb[2];
#pragma unroll
    for (int mi = 0; mi < 2; ++mi)
      a[mi] = *(const short8*)(Cs + (lBase + mi * 16 + (lane & 15)) * 128 + ks * 32 + (lane >> 4) * 8);
#pragma unroll
    for (int ni = 0; ni < 2; ++ni)
      bb[ni] = *(const short8*)(BsMs + (sBase + ni * 16 + (lane & 15)) * 128 + ks * 32 + (lane >> 4) * 8);
#pragma unroll
    for (int mi = 0; mi < 2; ++mi)
#pragma unroll
      for (int ni = 0; ni < 2; ++ni)
        g[mi][ni] = __builtin_amdgcn_mfma_f32_16x16x32_bf16(a[mi], bb[ni], g[mi][ni], 0, 0, 0);
  }
  __syncthreads();

  bf16* Ms = BsMs;                  // overwrite B region with masked scores
#pragma unroll
  for (int mi = 0; mi < 2; ++mi)
#pragma unroll
    for (int ni = 0; ni < 2; ++ni)
#pragma unroll
      for (int r = 0; r < 4; ++r) {
        int row = lBase + mi * 16 + (lane >> 4) * 4 + r;
        int col = sBase + ni * 16 + (lane & 15);
        float lm = (row >= col) ? expf(acs_s[row] - acs_s[col]) : 0.f;
        Ms[row * 64 + col] = __float2bfloat16(g[mi][ni][r] * lm);
      }
  __syncthreads();

  // Y_diag = Ms @ x  (K=64 over s),  Y_off = Cs @ Sp^T (K=128 over n)
  int pBase = (wid & 1) * 32;
  f32x4 yd[2][2] = {}, yo[2][2] = {};
#pragma unroll
  for (int ks = 0; ks < 2; ++ks) {
    short8 a[2], bb[2];
#pragma unroll
    for (int mi = 0; mi < 2; ++mi)
      a[mi] = *(const short8*)(Ms + (lBase + mi * 16 + (lane & 15)) * 64 + ks * 32 + (lane >> 4) * 8);
#pragma unroll
    for (int ni = 0; ni < 2; ++ni)
      bb[ni] = *(const short8*)(xT + (pBase + ni * 16 + (lane & 15)) * 64 + ks * 32 + (lane >> 4) * 8);
#pragma unroll
    for (int mi = 0; mi < 2; ++mi)
#pragma unroll
      for (int ni = 0; ni < 2; ++ni)
        yd[mi][ni] = __builtin_amdgcn_mfma_f32_16x16x32_bf16(a[mi], bb[ni], yd[mi][ni], 0, 0, 0);
  }
#pragma unroll
  for (int ks = 0; ks < 4; ++ks) {
    short8 a[2], bb[2];
#pragma unroll
    for (int mi = 0; mi < 2; ++mi)
      a[mi] = *(const short8*)(Cs + (lBase + mi * 16 + (lane & 15)) * 128 + ks * 32 + (lane >> 4) * 8);
#pragma unroll
    for (int ni = 0; ni < 2; ++ni)
      bb[ni] = *(const short8*)(Sp + (pBase + ni * 16 + (lane & 15)) * 128 + ks * 32 + (lane >> 4) * 8);
#pragma unroll
    for (int mi = 0; mi < 2; ++mi)
#pragma unroll
      for (int ni = 0; ni < 2; ++ni)
        yo[mi][ni] = __builtin_amdgcn_mfma_f32_16x16x32_bf16(a[mi], bb[ni], yo[mi][ni], 0, 0, 0);
  }
  __syncthreads();                  // all xT reads done before in-place write
#pragma unroll
  for (int mi = 0; mi < 2; ++mi)
#pragma unroll
    for (int ni = 0; ni < 2; ++ni)
#pragma unroll
      for (int r = 0; r < 4; ++r) {
        int lr = lBase + mi * 16 + (lane >> 4) * 4 + r;
        int p = pBase + ni * 16 + (lane & 15);
        float val = yd[mi][ni][r] + expf(acs_s[lr]) * yo[mi][ni][r];
        x_bf[(size_t)(tokBase + lr) * 4096 + h * 64 + p] = __float2bfloat16(val);
      }
}

// ---------------- launch ----------------
extern "C" void kernel_launch(void* const* d_in, const int* in_sizes, int n_in,
                              void* d_out, int out_size, void* d_ws, size_t ws_size,
                              hipStream_t stream) {
  const float* u       = (const float*)d_in[0];
  const float* W_in    = (const float*)d_in[1];
  const float* b_in    = (const float*)d_in[2];
  const float* W_out   = (const float*)d_in[3];
  const float* b_out   = (const float*)d_in[4];
  const float* A_log   = (const float*)d_in[5];
  const float* dt_bias = (const float*)d_in[6];

  float* y_out  = (float*)d_out;
  float* fs_out = y_out + (size_t)NTOK * MODEL_DIM;

  char* ws = (char*)d_ws;
  size_t off = 0;
  auto alloc = [&](size_t bytes) { char* p = ws + off; off += (bytes + 255) & ~255ull; return p; };
  bf16*  wout_bf = (bf16*) alloc((size_t)MODEL_DIM * INNER * 2);   // 16.8 MB
  bf16*  x_bf    = (bf16*) alloc((size_t)NTOK * INNER * 2);        // 67 MB (x, then y)
  bf16*  B_bf    = (bf16*) alloc((size_t)NTOK * STATE_DIM * 2);
  bf16*  C_bf    = (bf16*) alloc((size_t)NTOK * STATE_DIM * 2);
  float* dtraw   = (float*)alloc((size_t)NTOK * NHEADS * 4);
  float* dts     = (float*)alloc((size_t)NTOK * NHEADS * 4);
  float* a_dt    = (float*)alloc((size_t)NTOK * NHEADS * 4);
  float* acs     = (float*)alloc((size_t)BSZ * NCHUNK * NHEADS * 64 * 4);
  // region Q: states (bf16, 134 MB) aliased with {u_bf, win_bf} (dead after gemm_in)
  char*  Q       = alloc((size_t)BSZ * NCHUNK * NHEADS * 64 * 128 * 2);
  bf16*  states  = (bf16*)Q;
  bf16*  u_bf    = (bf16*)Q;
  bf16*  win_bf  = u_bf + (size_t)NTOK * MODEL_DIM;
  (void)ws_size; (void)off; (void)in_sizes; (void)n_in; (void)out_size;

  conv_f32_to_bf16<<<dim3(16384), dim3(256), 0, stream>>>(u, u_bf, NTOK * MODEL_DIM / 4);
  conv_win_pad<<<dim3(NPAD * MODEL_DIM / 1024), dim3(256), 0, stream>>>(W_in, win_bf);
  conv_f32_to_bf16<<<dim3(8192), dim3(256), 0, stream>>>(W_out, wout_bf, MODEL_DIM * INNER / 4);

  gemm_in256<<<dim3((NPAD / 256) * (NTOK / 256)), dim3(512), 0, stream>>>(
      u_bf, win_bf, b_in, x_bf, B_bf, C_bf, dtraw);

  prep_small<<<dim3(NTOK * NHEADS / 256), dim3(256), 0, stream>>>(dtraw, A_log, dt_bias, dts, a_dt);

  ssd_states_kernel<<<dim3(BSZ * NCHUNK * NHEADS), dim3(256), 0, stream>>>(
      x_bf, B_bf, dts, a_dt, acs, states);

  ssd_scan_kernel<<<dim3(BSZ * NHEADS * 4), dim3(256), 0, stream>>>(states, acs, fs_out);

  ssd_out_kernel<<<dim3(BSZ * NCHUNK * NHEADS), dim3(256), 0, stream>>>(
      x_bf, B_bf, C_bf, dts, acs, states);

  gemm_out256<<<dim3((MODEL_DIM / 256) * (NTOK / 256)), dim3(512), 0, stream>>>(
      x_bf, wout_bf, b_out, y_out);
}

// Round 6
// 588.300 us; speedup vs baseline: 1.2335x; 1.0934x over previous
//
#include <hip/hip_runtime.h>
#include <hip/hip_bf16.h>

typedef __hip_bfloat16 bf16;
typedef __attribute__((ext_vector_type(8))) short short8;
typedef __attribute__((ext_vector_type(4))) float f32x4;

#define MODEL_DIM 2048
#define INNER     4096
#define NHEADS    64
#define HEAD_DIM  64
#define STATE_DIM 128
#define IN_PROJ   4416
#define NPAD      4608        /* padded to 24*192 for the in-proj GEMM grid */
#define BSZ       2
#define SEQ       4096
#define CHUNKL    64
#define NTOK      (BSZ*SEQ)      /* 8192 */
#define NCHUNK    (SEQ/CHUNKL)   /* 64 */

#define WAITV0() asm volatile("s_waitcnt vmcnt(0)" ::: "memory")
#define BAR()    __builtin_amdgcn_s_barrier()
#define WAITLGKM() do { asm volatile("s_waitcnt lgkmcnt(0)" ::: "memory"); \
                        __builtin_amdgcn_sched_barrier(0); } while (0)

// swizzle: XOR the 16B-slot index (bits 4-6) with row&7 (bits 7-9). Involution.
#define SWZ(x) ((x) ^ ((((x) >> 7) & 7) << 4))

// ---------------- helpers ----------------
static __device__ __forceinline__ void gload_lds16(const bf16* g, bf16* l) {
  __builtin_amdgcn_global_load_lds((const __attribute__((address_space(1))) void*)g,
                                   (__attribute__((address_space(3))) void*)l, 16, 0, 0);
}

static __device__ __forceinline__ unsigned lds_u32(const void* p) {
  return (unsigned)(unsigned long long)(const __attribute__((address_space(3))) char*)p;
}

static __device__ __forceinline__ short8 ds_read128(unsigned addr) {
  short8 r;
  asm volatile("ds_read_b128 %0, %1" : "=v"(r) : "v"(addr));
  return r;
}

// stage one 8KB unit (64 rows x 64 cols bf16): 1 gload_lds per thread (512 thr x 16B).
// LDS dest linear; global source pre-permuted by the (involutory) swizzle.
static __device__ __forceinline__ void stage_unit(const bf16* __restrict__ P, int K,
                                                  int blockRow, int kt,
                                                  char* region, int unit, int t) {
  int o = unit * 8192 + (t << 4);
  int lb = SWZ(o);
  int row = lb >> 7, colb = lb & 127;
  gload_lds16(P + (size_t)(blockRow + row) * K + kt + (colb >> 1), (bf16*)(region + o));
}

// ---------------- 256xBN / BK=64 / 8-wave / 1-barrier-per-K-tile GEMM core ----------------
template<int BN>
static __device__ __forceinline__ void gemm_core1(
    const bf16* __restrict__ Ag, const bf16* __restrict__ Bg,
    int K, int NT, int bm, int bn, char* lds, f32x4 (&acc)[8][BN / 64]) {
  constexpr int NR = BN / 64;             // B frags per wave == B 64-row units
  constexpr int BB = 32768 + NR * 8192;   // bytes per (A+B) buffer
  const int t = threadIdx.x;
  const int lane = t & 63;
  const int wid = t >> 6, wm = wid >> 2, wn = wid & 3;
  const unsigned x16 = (unsigned)(lane & 7) << 4;     // read-side swizzle XOR
  const unsigned kb0 = (unsigned)(lane >> 4) << 4;    // 0,16,32,48
  const unsigned ldsB = lds_u32(lds);
  const unsigned aRow0 = (unsigned)(wm * 128 + (lane & 15)) * 128;
  const unsigned bRow0 = (unsigned)(wn * (BN / 4) + (lane & 15)) * 128;

  // prologue: tile 0 -> buf0
#pragma unroll
  for (int u = 0; u < 4; ++u) stage_unit(Ag, K, bm, 0, lds, u, t);
#pragma unroll
  for (int u = 0; u < NR; ++u) stage_unit(Bg, K, bn, 0, lds + 32768, u, t);
  WAITV0();
  BAR();

  int cur = 0;
  for (int tt = 0; tt < NT; ++tt) {
    char* oth = lds + (cur ^ 1) * BB;
    const unsigned aB = ldsB + (unsigned)(cur * BB);
    const unsigned bB = aB + 32768;
    const bool st = (tt + 1 < NT);

    if (st) {                               // stage t+1 -> other buffer (drained last phase)
      const int kt1 = (tt + 1) * 64;
#pragma unroll
      for (int u = 0; u < 4; ++u) stage_unit(Ag, K, bm, kt1, oth, u, t);
#pragma unroll
      for (int u = 0; u < NR; ++u) stage_unit(Bg, K, bn, kt1, oth + 32768, u, t);
    }

    short8 a[8][2], b[NR][2];
#pragma unroll
    for (int mf = 0; mf < 8; ++mf)
#pragma unroll
      for (int ks = 0; ks < 2; ++ks)
        a[mf][ks] = ds_read128(aB + aRow0 + mf * 2048 + (((unsigned)(ks * 64) + kb0) ^ x16));
#pragma unroll
    for (int nf = 0; nf < NR; ++nf)
#pragma unroll
      for (int ks = 0; ks < 2; ++ks)
        b[nf][ks] = ds_read128(bB + bRow0 + nf * 2048 + (((unsigned)(ks * 64) + kb0) ^ x16));
    WAITLGKM();

    __builtin_amdgcn_s_setprio(1);
#pragma unroll
    for (int mf = 0; mf < 8; ++mf)
#pragma unroll
      for (int nf = 0; nf < NR; ++nf)
#pragma unroll
        for (int ks = 0; ks < 2; ++ks)
          acc[mf][nf] = __builtin_amdgcn_mfma_f32_16x16x32_bf16(a[mf][ks], b[nf][ks], acc[mf][nf], 0, 0, 0);
    __builtin_amdgcn_s_setprio(0);

    if (st) WAITV0();                       // t+1 issued ~full phase ago: ~free
    BAR();                                  // single barrier per K-tile
    cur ^= 1;
  }
}

// in-proj GEMM (BN=192): routed epilogue (x->bf16, B->bf16, C->bf16, dt->f32)
__global__ __launch_bounds__(512, 2)
void gemm_in256(const bf16* __restrict__ A, const bf16* __restrict__ Bw,
                const float* __restrict__ bias, bf16* __restrict__ x_bf,
                bf16* __restrict__ B_bf, bf16* __restrict__ C_bf, float* __restrict__ dtraw) {
  __shared__ char lds[2 * (32768 + 3 * 8192)];
  int nwg = gridDim.x, bid = blockIdx.x;
  int cpx = nwg >> 3;
  int sb = (bid & 7) * cpx + (bid >> 3);       // bijective: nwg % 8 == 0
  int bx = sb % (NPAD / 192), by = sb / (NPAD / 192);
  int bm = by * 256, bn = bx * 192;
  f32x4 acc[8][3] = {};
  gemm_core1<192>(A, Bw, MODEL_DIM, MODEL_DIM / 64, bm, bn, lds, acc);
  const int lane = threadIdx.x & 63, wid = threadIdx.x >> 6;
  const int wm = wid >> 2, wn = wid & 3;
#pragma unroll
  for (int mf = 0; mf < 8; ++mf)
#pragma unroll
    for (int nf = 0; nf < 3; ++nf)
#pragma unroll
      for (int r = 0; r < 4; ++r) {
        int row = bm + wm * 128 + mf * 16 + (lane >> 4) * 4 + r;
        int col = bn + wn * 48 + nf * 16 + (lane & 15);
        float v = acc[mf][nf][r] + ((col < IN_PROJ) ? bias[col] : 0.f);
        if (col < 4096)       x_bf[(size_t)row * 4096 + col]         = __float2bfloat16(v);
        else if (col < 4224)  B_bf[(size_t)row * 128 + (col - 4096)] = __float2bfloat16(v);
        else if (col < 4352)  C_bf[(size_t)row * 128 + (col - 4224)] = __float2bfloat16(v);
        else if (col < 4416)  dtraw[(size_t)row * 64 + (col - 4352)] = v;
      }
}

// out-proj GEMM (BN=256): f32 output + bias
__global__ __launch_bounds__(512, 2)
void gemm_out256(const bf16* __restrict__ A, const bf16* __restrict__ Bw,
                 const float* __restrict__ bias, float* __restrict__ C) {
  __shared__ char lds[2 * (32768 + 4 * 8192)];
  int nwg = gridDim.x, bid = blockIdx.x;
  int cpx = nwg >> 3;
  int sb = (bid & 7) * cpx + (bid >> 3);
  int bx = sb % (MODEL_DIM / 256), by = sb / (MODEL_DIM / 256);
  int bm = by * 256, bn = bx * 256;
  f32x4 acc[8][4] = {};
  gemm_core1<256>(A, Bw, INNER, INNER / 64, bm, bn, lds, acc);
  const int lane = threadIdx.x & 63, wid = threadIdx.x >> 6;
  const int wm = wid >> 2, wn = wid & 3;
#pragma unroll
  for (int mf = 0; mf < 8; ++mf)
#pragma unroll
    for (int nf = 0; nf < 4; ++nf)
#pragma unroll
      for (int r = 0; r < 4; ++r) {
        int row = bm + wm * 128 + mf * 16 + (lane >> 4) * 4 + r;
        int col = bn + wn * 64 + nf * 16 + (lane & 15);
        C[(size_t)row * MODEL_DIM + col] = acc[mf][nf][r] + bias[col];
      }
}

// ---------------- converts ----------------
__global__ __launch_bounds__(256) void conv_f32_to_bf16(const float* __restrict__ src,
                                                        bf16* __restrict__ dst, int n4) {
  int i = blockIdx.x * 256 + threadIdx.x;
  if (i >= n4) return;
  float4 v = *(const float4*)(src + (size_t)i * 4);
  bf16* d = dst + (size_t)i * 4;
  d[0] = __float2bfloat16(v.x); d[1] = __float2bfloat16(v.y);
  d[2] = __float2bfloat16(v.z); d[3] = __float2bfloat16(v.w);
}

__global__ __launch_bounds__(256) void conv_win_pad(const float* __restrict__ W,
                                                    bf16* __restrict__ dst) {
  int i = blockIdx.x * 256 + threadIdx.x;      // over NPAD*2048/4
  int row = (i * 4) >> 11;
  int col = (i * 4) & 2047;
  bf16* d = dst + (size_t)i * 4;
  if (row < IN_PROJ) {
    float4 v = *(const float4*)(W + (size_t)row * 2048 + col);
    d[0] = __float2bfloat16(v.x); d[1] = __float2bfloat16(v.y);
    d[2] = __float2bfloat16(v.z); d[3] = __float2bfloat16(v.w);
  } else {
    bf16 z = __float2bfloat16(0.f);
    d[0] = z; d[1] = z; d[2] = z; d[3] = z;
  }
}

// ---------------- prep: dt tables only ----------------
__global__ __launch_bounds__(256)
void prep_small(const float* __restrict__ dtraw, const float* __restrict__ A_log,
                const float* __restrict__ dt_bias, float* __restrict__ dts,
                float* __restrict__ a_dt) {
  int i = blockIdx.x * 256 + threadIdx.x;      // NTOK*64
  int h = i & 63;
  float z = dtraw[i] + dt_bias[h];
  float dt = (z > 20.f) ? z : log1pf(expf(z));
  dts[i] = dt;
  a_dt[i] = -expf(A_log[h]) * dt;
}

// ---------------- intra-chunk states: states[b][c][h][p][n] (bf16) ----------------
__global__ __launch_bounds__(256)
void ssd_states_kernel(const bf16* __restrict__ x_bf, const bf16* __restrict__ B_bf,
                       const float* __restrict__ dts, const float* __restrict__ a_dt,
                       float* __restrict__ acs_g, bf16* __restrict__ states_g) {
  __shared__ bf16 xT[64 * 64];      // [p][l]
  __shared__ bf16 BdT[128 * 64];    // [n][l]
  __shared__ float acs_s[64];
  int blk = blockIdx.x;             // b*4096 + c*64 + h
  int h = blk & 63, c = (blk >> 6) & 63, b = blk >> 12;
  int t = threadIdx.x, lane = t & 63, wid = t >> 6;
  int tokBase = b * SEQ + c * 64;

  if (t < 64) {
    float v = a_dt[(size_t)(tokBase + t) * 64 + h];
#pragma unroll
    for (int d = 1; d < 64; d <<= 1) { float o = __shfl_up(v, d); if (t >= d) v += o; }
    acs_s[t] = v;
    acs_g[(((size_t)(b * 64 + c)) * 64 + h) * 64 + t] = v;
  }
  __syncthreads();
  float acs63 = acs_s[63];

#pragma unroll
  for (int i = 0; i < 2; ++i) {                         // x transpose (+ dt scale)
    int chunk = t + i * 256;
    int l = chunk >> 3, p0 = (chunk & 7) * 8;
    float dtv = dts[(size_t)(tokBase + l) * 64 + h];
    short8 vv = *(const short8*)(x_bf + (size_t)(tokBase + l) * 4096 + h * 64 + p0);
    const bf16* pv = (const bf16*)&vv;
#pragma unroll
    for (int j = 0; j < 8; ++j)
      xT[(p0 + j) * 64 + l] = __float2bfloat16(__bfloat162float(pv[j]) * dtv);
  }
#pragma unroll
  for (int i = 0; i < 4; ++i) {                         // B*decay transpose
    int chunk = t + i * 256;
    int l = chunk >> 4, n0 = (chunk & 15) * 8;
    float dec = expf(acs63 - acs_s[l]);
    short8 vv = *(const short8*)(B_bf + (size_t)(tokBase + l) * 128 + n0);
    const bf16* pv = (const bf16*)&vv;
#pragma unroll
    for (int j = 0; j < 8; ++j)
      BdT[(n0 + j) * 64 + l] = __float2bfloat16(__bfloat162float(pv[j]) * dec);
  }
  __syncthreads();

  int pBase = (wid >> 1) * 32, nBase = (wid & 1) * 64;
  f32x4 acc[2][4] = {};
#pragma unroll
  for (int ks = 0; ks < 2; ++ks) {
    short8 a[2], bb[4];
#pragma unroll
    for (int mi = 0; mi < 2; ++mi)
      a[mi] = *(const short8*)(xT + (pBase + mi * 16 + (lane & 15)) * 64 + ks * 32 + (lane >> 4) * 8);
#pragma unroll
    for (int ni = 0; ni < 4; ++ni)
      bb[ni] = *(const short8*)(BdT + (nBase + ni * 16 + (lane & 15)) * 64 + ks * 32 + (lane >> 4) * 8);
#pragma unroll
    for (int mi = 0; mi < 2; ++mi)
#pragma unroll
      for (int ni = 0; ni < 4; ++ni)
        acc[mi][ni] = __builtin_amdgcn_mfma_f32_16x16x32_bf16(a[mi], bb[ni], acc[mi][ni], 0, 0, 0);
  }
  size_t sbase = ((size_t)((b * 64 + c) * 64 + h)) * 64 * 128;
#pragma unroll
  for (int mi = 0; mi < 2; ++mi)
#pragma unroll
    for (int ni = 0; ni < 4; ++ni)
#pragma unroll
      for (int r = 0; r < 4; ++r) {
        int p = pBase + mi * 16 + (lane >> 4) * 4 + r;
        int n = nBase + ni * 16 + (lane & 15);
        states_g[sbase + (size_t)p * 128 + n] = __float2bfloat16(acc[mi][ni][r]);
      }
}

// ---------------- inter-chunk scan (in-place states -> states_prev, bf16) ----------------
__global__ __launch_bounds__(256)
void ssd_scan_kernel(bf16* __restrict__ states_g, const float* __restrict__ acs_g,
                     float* __restrict__ out_fs) {
  int blk = blockIdx.x;             // (b*64 + h)*4 + q
  int q = blk & 3, bh = blk >> 2;
  int b = bh >> 6, h = bh & 63;
  int t = threadIdx.x;
  int eb = q * 2048 + t;
  float S[8];
#pragma unroll
  for (int i = 0; i < 8; ++i) S[i] = 0.f;
  for (int c = 0; c < 64; ++c) {
    size_t base = ((size_t)((b * 64 + c) * 64 + h)) * 8192;
    float dfac = expf(acs_g[(((size_t)(b * 64 + c)) * 64 + h) * 64 + 63]);
#pragma unroll
    for (int i = 0; i < 8; ++i) {
      int e = eb + i * 256;
      float cs = __bfloat162float(states_g[base + e]);
      states_g[base + e] = __float2bfloat16(S[i]);
      S[i] = dfac * S[i] + cs;
    }
  }
  size_t ob = (size_t)bh * 8192;
#pragma unroll
  for (int i = 0; i < 8; ++i) out_fs[ob + eb + i * 256] = S[i];
}

// ---------------- output: Y_diag + Y_off -> y written in place into x_bf ----------------
__global__ __launch_bounds__(256)
void ssd_out_kernel(bf16* __restrict__ x_bf, const bf16* __restrict__ B_bf,
                    const bf16* __restrict__ C_bf, const float* __restrict__ dts,
                    const float* __restrict__ acs_g, const bf16* __restrict__ states_g) {
  __shared__ bf16 Cs[64 * 128];     // [l][n]
  __shared__ bf16 BsMs[64 * 128];   // [s][n]; first 8KB reused as Ms[l][s]
  __shared__ bf16 xT[64 * 64];      // [p][l]
  __shared__ bf16 Sp[64 * 128];     // [p][n]
  __shared__ float acs_s[64];
  int blk = blockIdx.x;
  int h = blk & 63, c = (blk >> 6) & 63, b = blk >> 12;
  int t = threadIdx.x, lane = t & 63, wid = t >> 6;
  int tokBase = b * SEQ + c * 64;
  size_t sbase = ((size_t)((b * 64 + c) * 64 + h)) * 8192;

  if (t < 64) acs_s[t] = acs_g[(((size_t)(b * 64 + c)) * 64 + h) * 64 + t];
#pragma unroll
  for (int i = 0; i < 4; ++i) {                         // C, B natural
    int chunk = t + i * 256;
    int l = chunk >> 4, n0 = (chunk & 15) * 8;
    *(short8*)(Cs + l * 128 + n0) = *(const short8*)(C_bf + (size_t)(tokBase + l) * 128 + n0);
    *(short8*)(BsMs + l * 128 + n0) = *(const short8*)(B_bf + (size_t)(tokBase + l) * 128 + n0);
  }
#pragma unroll
  for (int i = 0; i < 2; ++i) {                         // x transpose (+ dt scale)
    int chunk = t + i * 256;
    int l = chunk >> 3, p0 = (chunk & 7) * 8;
    float dtv = dts[(size_t)(tokBase + l) * 64 + h];
    short8 vv = *(const short8*)(x_bf + (size_t)(tokBase + l) * 4096 + h * 64 + p0);
    const bf16* pv = (const bf16*)&vv;
#pragma unroll
    for (int j = 0; j < 8; ++j)
      xT[(p0 + j) * 64 + l] = __float2bfloat16(__bfloat162float(pv[j]) * dtv);
  }
#pragma unroll
  for (int i = 0; i < 4; ++i) {                         // S_prev bf16 -> LDS
    int chunk = t + i * 256;
    *(short8*)(Sp + chunk * 8) = *(const short8*)(states_g + sbase + chunk * 8);
  }
  __syncthreads();

  // G = C * B^T  (64x64, K=128)
  int lBase = (wid >> 1) * 32, sBase = (wid & 1) * 32;
  f32x4 g[2][2] = {};
#pragma unroll
  for (int ks = 0; ks < 4; ++ks) {
    short8 a[2], bb[2];
#pragma unroll
    for (int mi = 0; mi < 2; ++mi)
      a[mi] = *(const short8*)(Cs + (lBase + mi * 16 + (lane & 15)) * 128 + ks * 32 + (lane >> 4) * 8);
#pragma unroll
    for (int ni = 0; ni < 2; ++ni)
      bb[ni] = *(const short8*)(BsMs + (sBase + ni * 16 + (lane & 15)) * 128 + ks * 32 + (lane >> 4) * 8);
#pragma unroll
    for (int mi = 0; mi < 2; ++mi)
#pragma unroll
      for (int ni = 0; ni < 2; ++ni)
        g[mi][ni] = __builtin_amdgcn_mfma_f32_16x16x32_bf16(a[mi], bb[ni], g[mi][ni], 0, 0, 0);
  }
  __syncthreads();

  bf16* Ms = BsMs;                  // overwrite B region with masked scores
#pragma unroll
  for (int mi = 0; mi < 2; ++mi)
#pragma unroll
    for (int ni = 0; ni < 2; ++ni)
#pragma unroll
      for (int r = 0; r < 4; ++r) {
        int row = lBase + mi * 16 + (lane >> 4) * 4 + r;
        int col = sBase + ni * 16 + (lane & 15);
        float lm = (row >= col) ? expf(acs_s[row] - acs_s[col]) : 0.f;
        Ms[row * 64 + col] = __float2bfloat16(g[mi][ni][r] * lm);
      }
  __syncthreads();

  // Y_diag = Ms @ x  (K=64 over s),  Y_off = Cs @ Sp^T (K=128 over n)
  int pBase = (wid & 1) * 32;
  f32x4 yd[2][2] = {}, yo[2][2] = {};
#pragma unroll
  for (int ks = 0; ks < 2; ++ks) {
    short8 a[2], bb[2];
#pragma unroll
    for (int mi = 0; mi < 2; ++mi)
      a[mi] = *(const short8*)(Ms + (lBase + mi * 16 + (lane & 15)) * 64 + ks * 32 + (lane >> 4) * 8);
#pragma unroll
    for (int ni = 0; ni < 2; ++ni)
      bb[ni] = *(const short8*)(xT + (pBase + ni * 16 + (lane & 15)) * 64 + ks * 32 + (lane >> 4) * 8);
#pragma unroll
    for (int mi = 0; mi < 2; ++mi)
#pragma unroll
      for (int ni = 0; ni < 2; ++ni)
        yd[mi][ni] = __builtin_amdgcn_mfma_f32_16x16x32_bf16(a[mi], bb[ni], yd[mi][ni], 0, 0, 0);
  }
#pragma unroll
  for (int ks = 0; ks < 4; ++ks) {
    short8 a[2], bb[2];
#pragma unroll
    for (int mi = 0; mi < 2; ++mi)
      a[mi] = *(const short8*)(Cs + (lBase + mi * 16 + (lane & 15)) * 128 + ks * 32 + (lane >> 4) * 8);
#pragma unroll
    for (int ni = 0; ni < 2; ++ni)
      bb[ni] = *(const short8*)(Sp + (pBase + ni * 16 + (lane & 15)) * 128 + ks * 32 + (lane >> 4) * 8);
#pragma unroll
    for (int mi = 0; mi < 2; ++mi)
#pragma unroll
      for (int ni = 0; ni < 2; ++ni)
        yo[mi][ni] = __builtin_amdgcn_mfma_f32_16x16x32_bf16(a[mi], bb[ni], yo[mi][ni], 0, 0, 0);
  }
  __syncthreads();                  // all xT reads done before in-place write
#pragma unroll
  for (int mi = 0; mi < 2; ++mi)
#pragma unroll
    for (int ni = 0; ni < 2; ++ni)
#pragma unroll
      for (int r = 0; r < 4; ++r) {
        int lr = lBase + mi * 16 + (lane >> 4) * 4 + r;
        int p = pBase + ni * 16 + (lane & 15);
        float val = yd[mi][ni][r] + expf(acs_s[lr]) * yo[mi][ni][r];
        x_bf[(size_t)(tokBase + lr) * 4096 + h * 64 + p] = __float2bfloat16(val);
      }
}

// ---------------- launch ----------------
extern "C" void kernel_launch(void* const* d_in, const int* in_sizes, int n_in,
                              void* d_out, int out_size, void* d_ws, size_t ws_size,
                              hipStream_t stream) {
  const float* u       = (const float*)d_in[0];
  const float* W_in    = (const float*)d_in[1];
  const float* b_in    = (const float*)d_in[2];
  const float* W_out   = (const float*)d_in[3];
  const float* b_out   = (const float*)d_in[4];
  const float* A_log   = (const float*)d_in[5];
  const float* dt_bias = (const float*)d_in[6];

  float* y_out  = (float*)d_out;
  float* fs_out = y_out + (size_t)NTOK * MODEL_DIM;

  char* ws = (char*)d_ws;
  size_t off = 0;
  auto alloc = [&](size_t bytes) { char* p = ws + off; off += (bytes + 255) & ~255ull; return p; };
  bf16*  wout_bf = (bf16*) alloc((size_t)MODEL_DIM * INNER * 2);   // 16.8 MB
  bf16*  x_bf    = (bf16*) alloc((size_t)NTOK * INNER * 2);        // 67 MB (x, then y)
  bf16*  B_bf    = (bf16*) alloc((size_t)NTOK * STATE_DIM * 2);
  bf16*  C_bf    = (bf16*) alloc((size_t)NTOK * STATE_DIM * 2);
  float* dtraw   = (float*)alloc((size_t)NTOK * NHEADS * 4);
  float* dts     = (float*)alloc((size_t)NTOK * NHEADS * 4);
  float* a_dt    = (float*)alloc((size_t)NTOK * NHEADS * 4);
  float* acs     = (float*)alloc((size_t)BSZ * NCHUNK * NHEADS * 64 * 4);
  // region Q: states (bf16, 134 MB) aliased with {u_bf, win_bf} (dead after gemm_in)
  char*  Q       = alloc((size_t)BSZ * NCHUNK * NHEADS * 64 * 128 * 2);
  bf16*  states  = (bf16*)Q;
  bf16*  u_bf    = (bf16*)Q;
  bf16*  win_bf  = u_bf + (size_t)NTOK * MODEL_DIM;
  (void)ws_size; (void)off; (void)in_sizes; (void)n_in; (void)out_size;

  conv_f32_to_bf16<<<dim3(16384), dim3(256), 0, stream>>>(u, u_bf, NTOK * MODEL_DIM / 4);
  conv_win_pad<<<dim3(NPAD * MODEL_DIM / 1024), dim3(256), 0, stream>>>(W_in, win_bf);
  conv_f32_to_bf16<<<dim3(8192), dim3(256), 0, stream>>>(W_out, wout_bf, MODEL_DIM * INNER / 4);

  gemm_in256<<<dim3((NTOK / 256) * (NPAD / 192)), dim3(512), 0, stream>>>(
      u_bf, win_bf, b_in, x_bf, B_bf, C_bf, dtraw);

  prep_small<<<dim3(NTOK * NHEADS / 256), dim3(256), 0, stream>>>(dtraw, A_log, dt_bias, dts, a_dt);

  ssd_states_kernel<<<dim3(BSZ * NCHUNK * NHEADS), dim3(256), 0, stream>>>(
      x_bf, B_bf, dts, a_dt, acs, states);

  ssd_scan_kernel<<<dim3(BSZ * NHEADS * 4), dim3(256), 0, stream>>>(states, acs, fs_out);

  ssd_out_kernel<<<dim3(BSZ * NCHUNK * NHEADS), dim3(256), 0, stream>>>(
      x_bf, B_bf, C_bf, dts, acs, states);

  gemm_out256<<<dim3((MODEL_DIM / 256) * (NTOK / 256)), dim3(512), 0, stream>>>(
      x_bf, wout_bf, b_out, y_out);
}

// Round 8
// 584.220 us; speedup vs baseline: 1.2421x; 1.0070x over previous
//
#include <hip/hip_runtime.h>
#include <hip/hip_bf16.h>

typedef __hip_bfloat16 bf16;
typedef __attribute__((ext_vector_type(8))) short short8;
typedef __attribute__((ext_vector_type(4))) float f32x4;

#define MODEL_DIM 2048
#define INNER     4096
#define NHEADS    64
#define HEAD_DIM  64
#define STATE_DIM 128
#define IN_PROJ   4416
#define NPAD      4608        /* padded to 24*192 for the in-proj GEMM grid */
#define BSZ       2
#define SEQ       4096
#define CHUNKL    64
#define NTOK      (BSZ*SEQ)      /* 8192 */
#define NCHUNK    (SEQ/CHUNKL)   /* 64 */

#define WAITV0() asm volatile("s_waitcnt vmcnt(0)" ::: "memory")
#define BAR()    __builtin_amdgcn_s_barrier()
#define SCHEDB() __builtin_amdgcn_sched_barrier(0)
#define WAITLG(N) do { asm volatile("s_waitcnt lgkmcnt(" #N ")" ::: "memory"); SCHEDB(); } while (0)

// swizzle: XOR the 16B-slot index (bits 4-6) with row&7 (bits 7-9). Involution.
#define SWZ(x) ((x) ^ ((((x) >> 7) & 7) << 4))

// ---------------- helpers ----------------
static __device__ __forceinline__ void gload_lds16(const bf16* g, bf16* l) {
  __builtin_amdgcn_global_load_lds((const __attribute__((address_space(1))) void*)g,
                                   (__attribute__((address_space(3))) void*)l, 16, 0, 0);
}

static __device__ __forceinline__ unsigned lds_u32(const void* p) {
  return (unsigned)(unsigned long long)(const __attribute__((address_space(3))) char*)p;
}

static __device__ __forceinline__ short8 ds_read128(unsigned addr) {
  short8 r;
  asm volatile("ds_read_b128 %0, %1" : "=v"(r) : "v"(addr));
  return r;
}

// stage one 8KB unit (64 rows x 64 cols bf16): 1 gload_lds per thread (512 thr x 16B).
// LDS dest linear; global source pre-permuted by the (involutory) swizzle.
static __device__ __forceinline__ void stage_unit(const bf16* __restrict__ P, int K,
                                                  int blockRow, int kt,
                                                  char* region, int unit, int t) {
  int o = unit * 8192 + (t << 4);
  int lb = SWZ(o);
  int row = lb >> 7, colb = lb & 127;
  gload_lds16(P + (size_t)(blockRow + row) * K + kt + (colb >> 1), (bf16*)(region + o));
}

#define MFMA_BLK(MLO, MHI, NLO, NHI)                                                    \
  __builtin_amdgcn_s_setprio(1);                                                       \
  _Pragma("unroll") for (int mf = (MLO); mf < (MHI); ++mf)                             \
    _Pragma("unroll") for (int nf = (NLO); nf < (NHI); ++nf)                           \
      _Pragma("unroll") for (int ks = 0; ks < 2; ++ks)                                 \
        acc[mf][nf] = __builtin_amdgcn_mfma_f32_16x16x32_bf16(a[mf][ks], b[nf][ks],    \
                                                              acc[mf][nf], 0, 0, 0);  \
  __builtin_amdgcn_s_setprio(0);

// ---------------- 256xBN / BK=64 / 8-wave / counted-lgkm pipelined GEMM core ----------------
template<int BN>
static __device__ __forceinline__ void gemm_core1(
    const bf16* __restrict__ Ag, const bf16* __restrict__ Bg,
    int K, int NT, int bm, int bn, char* lds, f32x4 (&acc)[8][BN / 64]) {
  constexpr int NR = BN / 64;             // B frags per wave == B 64-row units
  constexpr int BB = 32768 + NR * 8192;   // bytes per (A+B) buffer
  const int t = threadIdx.x;
  const int lane = t & 63;
  const int wid = t >> 6, wm = wid >> 2, wn = wid & 3;
  const unsigned x16 = (unsigned)(lane & 7) << 4;     // read-side swizzle XOR
  const unsigned kb0 = (unsigned)(lane >> 4) << 4;    // 0,16,32,48
  const unsigned ldsB = lds_u32(lds);
  const unsigned aRow0 = (unsigned)(wm * 128 + (lane & 15)) * 128;
  const unsigned bRow0 = (unsigned)(wn * (BN / 4) + (lane & 15)) * 128;

  // prologue: tile 0 -> buf0
#pragma unroll
  for (int u = 0; u < 4; ++u) stage_unit(Ag, K, bm, 0, lds, u, t);
#pragma unroll
  for (int u = 0; u < NR; ++u) stage_unit(Bg, K, bn, 0, lds + 32768, u, t);
  WAITV0();
  BAR();

  int cur = 0;
  for (int tt = 0; tt < NT; ++tt) {
    char* oth = lds + (cur ^ 1) * BB;
    const unsigned aB = ldsB + (unsigned)(cur * BB);
    const unsigned bB = aB + 32768;
    const bool st = (tt + 1 < NT);

    if (st) {                               // stage t+1 -> other buffer (drained last phase)
      const int kt1 = (tt + 1) * 64;
#pragma unroll
      for (int u = 0; u < 4; ++u) stage_unit(Ag, K, bm, kt1, oth, u, t);
#pragma unroll
      for (int u = 0; u < NR; ++u) stage_unit(Bg, K, bn, kt1, oth + 32768, u, t);
    }

    short8 a[8][2], b[NR][2];
    // ---- ds_read issue, dependency order (DS retires in order):
    // g1: a-lo (8)
#pragma unroll
    for (int mf = 0; mf < 4; ++mf)
#pragma unroll
      for (int ks = 0; ks < 2; ++ks)
        a[mf][ks] = ds_read128(aB + aRow0 + mf * 2048 + (((unsigned)(ks * 64) + kb0) ^ x16));
    // g2: b-lo (4)
#pragma unroll
    for (int nf = 0; nf < 2; ++nf)
#pragma unroll
      for (int ks = 0; ks < 2; ++ks)
        b[nf][ks] = ds_read128(bB + bRow0 + nf * 2048 + (((unsigned)(ks * 64) + kb0) ^ x16));
    // g3: a-hi (8)
#pragma unroll
    for (int mf = 4; mf < 8; ++mf)
#pragma unroll
      for (int ks = 0; ks < 2; ++ks)
        a[mf][ks] = ds_read128(aB + aRow0 + mf * 2048 + (((unsigned)(ks * 64) + kb0) ^ x16));
    // g4: b-hi (2*(NR-2))
#pragma unroll
    for (int nf = 2; nf < NR; ++nf)
#pragma unroll
      for (int ks = 0; ks < 2; ++ks)
        b[nf][ks] = ds_read128(bB + bRow0 + nf * 2048 + (((unsigned)(ks * 64) + kb0) ^ x16));

    // ---- MFMA pipelined against the read drain (counted lgkm; DS in-order)
    if constexpr (NR == 4) WAITLG(12); else WAITLG(10);   // g1+g2 landed
    MFMA_BLK(0, 4, 0, 2);                                  // Q(m-lo, b-lo)
    if constexpr (NR == 4) WAITLG(4);  else WAITLG(2);    // +g3 landed
    MFMA_BLK(4, 8, 0, 2);                                  // Q(m-hi, b-lo)
    WAITLG(0);                                             // all landed
    MFMA_BLK(0, 8, 2, NR);                                 // remaining n-frags

    if (st) WAITV0();                       // t+1 stages issued ~full tile ago: ~free
    BAR();                                  // single barrier per K-tile
    cur ^= 1;
  }
}

// in-proj GEMM (BN=192): routed epilogue (x->bf16, B->bf16, C->bf16, dt->f32)
__global__ __launch_bounds__(512, 2)
void gemm_in256(const bf16* __restrict__ A, const bf16* __restrict__ Bw,
                const float* __restrict__ bias, bf16* __restrict__ x_bf,
                bf16* __restrict__ B_bf, bf16* __restrict__ C_bf, float* __restrict__ dtraw) {
  __shared__ char lds[2 * (32768 + 3 * 8192)];
  int nwg = gridDim.x, bid = blockIdx.x;
  int cpx = nwg >> 3;
  int sb = (bid & 7) * cpx + (bid >> 3);       // bijective: nwg % 8 == 0
  int bx = sb % (NPAD / 192), by = sb / (NPAD / 192);
  int bm = by * 256, bn = bx * 192;
  f32x4 acc[8][3] = {};
  gemm_core1<192>(A, Bw, MODEL_DIM, MODEL_DIM / 64, bm, bn, lds, acc);
  const int lane = threadIdx.x & 63, wid = threadIdx.x >> 6;
  const int wm = wid >> 2, wn = wid & 3;
#pragma unroll
  for (int mf = 0; mf < 8; ++mf)
#pragma unroll
    for (int nf = 0; nf < 3; ++nf)
#pragma unroll
      for (int r = 0; r < 4; ++r) {
        int row = bm + wm * 128 + mf * 16 + (lane >> 4) * 4 + r;
        int col = bn + wn * 48 + nf * 16 + (lane & 15);
        float v = acc[mf][nf][r] + ((col < IN_PROJ) ? bias[col] : 0.f);
        if (col < 4096)       x_bf[(size_t)row * 4096 + col]         = __float2bfloat16(v);
        else if (col < 4224)  B_bf[(size_t)row * 128 + (col - 4096)] = __float2bfloat16(v);
        else if (col < 4352)  C_bf[(size_t)row * 128 + (col - 4224)] = __float2bfloat16(v);
        else if (col < 4416)  dtraw[(size_t)row * 64 + (col - 4352)] = v;
      }
}

// out-proj GEMM (BN=256): f32 output + bias
__global__ __launch_bounds__(512, 2)
void gemm_out256(const bf16* __restrict__ A, const bf16* __restrict__ Bw,
                 const float* __restrict__ bias, float* __restrict__ C) {
  __shared__ char lds[2 * (32768 + 4 * 8192)];
  int nwg = gridDim.x, bid = blockIdx.x;
  int cpx = nwg >> 3;
  int sb = (bid & 7) * cpx + (bid >> 3);
  int bx = sb % (MODEL_DIM / 256), by = sb / (MODEL_DIM / 256);
  int bm = by * 256, bn = bx * 256;
  f32x4 acc[8][4] = {};
  gemm_core1<256>(A, Bw, INNER, INNER / 64, bm, bn, lds, acc);
  const int lane = threadIdx.x & 63, wid = threadIdx.x >> 6;
  const int wm = wid >> 2, wn = wid & 3;
#pragma unroll
  for (int mf = 0; mf < 8; ++mf)
#pragma unroll
    for (int nf = 0; nf < 4; ++nf)
#pragma unroll
      for (int r = 0; r < 4; ++r) {
        int row = bm + wm * 128 + mf * 16 + (lane >> 4) * 4 + r;
        int col = bn + wn * 64 + nf * 16 + (lane & 15);
        C[(size_t)row * MODEL_DIM + col] = acc[mf][nf][r] + bias[col];
      }
}

// ---------------- converts ----------------
__global__ __launch_bounds__(256) void conv_f32_to_bf16(const float* __restrict__ src,
                                                        bf16* __restrict__ dst, int n4) {
  int i = blockIdx.x * 256 + threadIdx.x;
  if (i >= n4) return;
  float4 v = *(const float4*)(src + (size_t)i * 4);
  bf16* d = dst + (size_t)i * 4;
  d[0] = __float2bfloat16(v.x); d[1] = __float2bfloat16(v.y);
  d[2] = __float2bfloat16(v.z); d[3] = __float2bfloat16(v.w);
}

__global__ __launch_bounds__(256) void conv_win_pad(const float* __restrict__ W,
                                                    bf16* __restrict__ dst) {
  int i = blockIdx.x * 256 + threadIdx.x;      // over NPAD*2048/4
  int row = (i * 4) >> 11;
  int col = (i * 4) & 2047;
  bf16* d = dst + (size_t)i * 4;
  if (row < IN_PROJ) {
    float4 v = *(const float4*)(W + (size_t)row * 2048 + col);
    d[0] = __float2bfloat16(v.x); d[1] = __float2bfloat16(v.y);
    d[2] = __float2bfloat16(v.z); d[3] = __float2bfloat16(v.w);
  } else {
    bf16 z = __float2bfloat16(0.f);
    d[0] = z; d[1] = z; d[2] = z; d[3] = z;
  }
}

// ---------------- prep: dt tables only ----------------
__global__ __launch_bounds__(256)
void prep_small(const float* __restrict__ dtraw, const float* __restrict__ A_log,
                const float* __restrict__ dt_bias, float* __restrict__ dts,
                float* __restrict__ a_dt) {
  int i = blockIdx.x * 256 + threadIdx.x;      // NTOK*64
  int h = i & 63;
  float z = dtraw[i] + dt_bias[h];
  float dt = (z > 20.f) ? z : log1pf(expf(z));
  dts[i] = dt;
  a_dt[i] = -expf(A_log[h]) * dt;
}

// ---------------- intra-chunk states: states[b][c][h][p][n] (bf16) ----------------
__global__ __launch_bounds__(256)
void ssd_states_kernel(const bf16* __restrict__ x_bf, const bf16* __restrict__ B_bf,
                       const float* __restrict__ dts, const float* __restrict__ a_dt,
                       float* __restrict__ acs_g, bf16* __restrict__ states_g) {
  __shared__ bf16 xT[64 * 64];      // [p][l]
  __shared__ bf16 BdT[128 * 64];    // [n][l]
  __shared__ float acs_s[64];
  int blk = blockIdx.x;             // b*4096 + c*64 + h
  int h = blk & 63, c = (blk >> 6) & 63, b = blk >> 12;
  int t = threadIdx.x, lane = t & 63, wid = t >> 6;
  int tokBase = b * SEQ + c * 64;

  if (t < 64) {
    float v = a_dt[(size_t)(tokBase + t) * 64 + h];
#pragma unroll
    for (int d = 1; d < 64; d <<= 1) { float o = __shfl_up(v, d); if (t >= d) v += o; }
    acs_s[t] = v;
    acs_g[(((size_t)(b * 64 + c)) * 64 + h) * 64 + t] = v;
  }
  __syncthreads();
  float acs63 = acs_s[63];

#pragma unroll
  for (int i = 0; i < 2; ++i) {                         // x transpose (+ dt scale)
    int chunk = t + i * 256;
    int l = chunk >> 3, p0 = (chunk & 7) * 8;
    float dtv = dts[(size_t)(tokBase + l) * 64 + h];
    short8 vv = *(const short8*)(x_bf + (size_t)(tokBase + l) * 4096 + h * 64 + p0);
    const bf16* pv = (const bf16*)&vv;
#pragma unroll
    for (int j = 0; j < 8; ++j)
      xT[(p0 + j) * 64 + l] = __float2bfloat16(__bfloat162float(pv[j]) * dtv);
  }
#pragma unroll
  for (int i = 0; i < 4; ++i) {                         // B*decay transpose
    int chunk = t + i * 256;
    int l = chunk >> 4, n0 = (chunk & 15) * 8;
    float dec = expf(acs63 - acs_s[l]);
    short8 vv = *(const short8*)(B_bf + (size_t)(tokBase + l) * 128 + n0);
    const bf16* pv = (const bf16*)&vv;
#pragma unroll
    for (int j = 0; j < 8; ++j)
      BdT[(n0 + j) * 64 + l] = __float2bfloat16(__bfloat162float(pv[j]) * dec);
  }
  __syncthreads();

  int pBase = (wid >> 1) * 32, nBase = (wid & 1) * 64;
  f32x4 acc[2][4] = {};
#pragma unroll
  for (int ks = 0; ks < 2; ++ks) {
    short8 a[2], bb[4];
#pragma unroll
    for (int mi = 0; mi < 2; ++mi)
      a[mi] = *(const short8*)(xT + (pBase + mi * 16 + (lane & 15)) * 64 + ks * 32 + (lane >> 4) * 8);
#pragma unroll
    for (int ni = 0; ni < 4; ++ni)
      bb[ni] = *(const short8*)(BdT + (nBase + ni * 16 + (lane & 15)) * 64 + ks * 32 + (lane >> 4) * 8);
#pragma unroll
    for (int mi = 0; mi < 2; ++mi)
#pragma unroll
      for (int ni = 0; ni < 4; ++ni)
        acc[mi][ni] = __builtin_amdgcn_mfma_f32_16x16x32_bf16(a[mi], bb[ni], acc[mi][ni], 0, 0, 0);
  }
  size_t sbase = ((size_t)((b * 64 + c) * 64 + h)) * 64 * 128;
#pragma unroll
  for (int mi = 0; mi < 2; ++mi)
#pragma unroll
    for (int ni = 0; ni < 4; ++ni)
#pragma unroll
      for (int r = 0; r < 4; ++r) {
        int p = pBase + mi * 16 + (lane >> 4) * 4 + r;
        int n = nBase + ni * 16 + (lane & 15);
        states_g[sbase + (size_t)p * 128 + n] = __float2bfloat16(acc[mi][ni][r]);
      }
}

// ---------------- inter-chunk scan (in-place states -> states_prev, bf16) ----------------
__global__ __launch_bounds__(256)
void ssd_scan_kernel(bf16* __restrict__ states_g, const float* __restrict__ acs_g,
                     float* __restrict__ out_fs) {
  int blk = blockIdx.x;             // (b*64 + h)*4 + q
  int q = blk & 3, bh = blk >> 2;
  int b = bh >> 6, h = bh & 63;
  int t = threadIdx.x;
  int eb = q * 2048 + t;
  float S[8];
#pragma unroll
  for (int i = 0; i < 8; ++i) S[i] = 0.f;
  for (int c = 0; c < 64; ++c) {
    size_t base = ((size_t)((b * 64 + c) * 64 + h)) * 8192;
    float dfac = expf(acs_g[(((size_t)(b * 64 + c)) * 64 + h) * 64 + 63]);
#pragma unroll
    for (int i = 0; i < 8; ++i) {
      int e = eb + i * 256;
      float cs = __bfloat162float(states_g[base + e]);
      states_g[base + e] = __float2bfloat16(S[i]);
      S[i] = dfac * S[i] + cs;
    }
  }
  size_t ob = (size_t)bh * 8192;
#pragma unroll
  for (int i = 0; i < 8; ++i) out_fs[ob + eb + i * 256] = S[i];
}

// ---------------- output: Y_diag + Y_off -> y written in place into x_bf ----------------
__global__ __launch_bounds__(256)
void ssd_out_kernel(bf16* __restrict__ x_bf, const bf16* __restrict__ B_bf,
                    const bf16* __restrict__ C_bf, const float* __restrict__ dts,
                    const float* __restrict__ acs_g, const bf16* __restrict__ states_g) {
  __shared__ bf16 Cs[64 * 128];     // [l][n]
  __shared__ bf16 BsMs[64 * 128];   // [s][n]; first 8KB reused as Ms[l][s]
  __shared__ bf16 xT[64 * 64];      // [p][l]
  __shared__ bf16 Sp[64 * 128];     // [p][n]
  __shared__ float acs_s[64];
  int blk = blockIdx.x;
  int h = blk & 63, c = (blk >> 6) & 63, b = blk >> 12;
  int t = threadIdx.x, lane = t & 63, wid = t >> 6;
  int tokBase = b * SEQ + c * 64;
  size_t sbase = ((size_t)((b * 64 + c) * 64 + h)) * 8192;

  if (t < 64) acs_s[t] = acs_g[(((size_t)(b * 64 + c)) * 64 + h) * 64 + t];
#pragma unroll
  for (int i = 0; i < 4; ++i) {                         // C, B natural
    int chunk = t + i * 256;
    int l = chunk >> 4, n0 = (chunk & 15) * 8;
    *(short8*)(Cs + l * 128 + n0) = *(const short8*)(C_bf + (size_t)(tokBase + l) * 128 + n0);
    *(short8*)(BsMs + l * 128 + n0) = *(const short8*)(B_bf + (size_t)(tokBase + l) * 128 + n0);
  }
#pragma unroll
  for (int i = 0; i < 2; ++i) {                         // x transpose (+ dt scale)
    int chunk = t + i * 256;
    int l = chunk >> 3, p0 = (chunk & 7) * 8;
    float dtv = dts[(size_t)(tokBase + l) * 64 + h];
    short8 vv = *(const short8*)(x_bf + (size_t)(tokBase + l) * 4096 + h * 64 + p0);
    const bf16* pv = (const bf16*)&vv;
#pragma unroll
    for (int j = 0; j < 8; ++j)
      xT[(p0 + j) * 64 + l] = __float2bfloat16(__bfloat162float(pv[j]) * dtv);
  }
#pragma unroll
  for (int i = 0; i < 4; ++i) {                         // S_prev bf16 -> LDS
    int chunk = t + i * 256;
    *(short8*)(Sp + chunk * 8) = *(const short8*)(states_g + sbase + chunk * 8);
  }
  __syncthreads();

  // G = C * B^T  (64x64, K=128)
  int lBase = (wid >> 1) * 32, sBase = (wid & 1) * 32;
  f32x4 g[2][2] = {};
#pragma unroll
  for (int ks = 0; ks < 4; ++ks) {
    short8 a[2], bb[2];
#pragma unroll
    for (int mi = 0; mi < 2; ++mi)
      a[mi] = *(const short8*)(Cs + (lBase + mi * 16 + (lane & 15)) * 128 + ks * 32 + (lane >> 4) * 8);
#pragma unroll
    for (int ni = 0; ni < 2; ++ni)
      bb[ni] = *(const short8*)(BsMs + (sBase + ni * 16 + (lane & 15)) * 128 + ks * 32 + (lane >> 4) * 8);
#pragma unroll
    for (int mi = 0; mi < 2; ++mi)
#pragma unroll
      for (int ni = 0; ni < 2; ++ni)
        g[mi][ni] = __builtin_amdgcn_mfma_f32_16x16x32_bf16(a[mi], bb[ni], g[mi][ni], 0, 0, 0);
  }
  __syncthreads();

  bf16* Ms = BsMs;                  // overwrite B region with masked scores
#pragma unroll
  for (int mi = 0; mi < 2; ++mi)
#pragma unroll
    for (int ni = 0; ni < 2; ++ni)
#pragma unroll
      for (int r = 0; r < 4; ++r) {
        int row = lBase + mi * 16 + (lane >> 4) * 4 + r;
        int col = sBase + ni * 16 + (lane & 15);
        float lm = (row >= col) ? expf(acs_s[row] - acs_s[col]) : 0.f;
        Ms[row * 64 + col] = __float2bfloat16(g[mi][ni][r] * lm);
      }
  __syncthreads();

  // Y_diag = Ms @ x  (K=64 over s),  Y_off = Cs @ Sp^T (K=128 over n)
  int pBase = (wid & 1) * 32;
  f32x4 yd[2][2] = {}, yo[2][2] = {};
#pragma unroll
  for (int ks = 0; ks < 2; ++ks) {
    short8 a[2], bb[2];
#pragma unroll
    for (int mi = 0; mi < 2; ++mi)
      a[mi] = *(const short8*)(Ms + (lBase + mi * 16 + (lane & 15)) * 64 + ks * 32 + (lane >> 4) * 8);
#pragma unroll
    for (int ni = 0; ni < 2; ++ni)
      bb[ni] = *(const short8*)(xT + (pBase + ni * 16 + (lane & 15)) * 64 + ks * 32 + (lane >> 4) * 8);
#pragma unroll
    for (int mi = 0; mi < 2; ++mi)
#pragma unroll
      for (int ni = 0; ni < 2; ++ni)
        yd[mi][ni] = __builtin_amdgcn_mfma_f32_16x16x32_bf16(a[mi], bb[ni], yd[mi][ni], 0, 0, 0);
  }
#pragma unroll
  for (int ks = 0; ks < 4; ++ks) {
    short8 a[2], bb[2];
#pragma unroll
    for (int mi = 0; mi < 2; ++mi)
      a[mi] = *(const short8*)(Cs + (lBase + mi * 16 + (lane & 15)) * 128 + ks * 32 + (lane >> 4) * 8);
#pragma unroll
    for (int ni = 0; ni < 2; ++ni)
      bb[ni] = *(const short8*)(Sp + (pBase + ni * 16 + (lane & 15)) * 128 + ks * 32 + (lane >> 4) * 8);
#pragma unroll
    for (int mi = 0; mi < 2; ++mi)
#pragma unroll
      for (int ni = 0; ni < 2; ++ni)
        yo[mi][ni] = __builtin_amdgcn_mfma_f32_16x16x32_bf16(a[mi], bb[ni], yo[mi][ni], 0, 0, 0);
  }
  __syncthreads();                  // all xT reads done before in-place write
#pragma unroll
  for (int mi = 0; mi < 2; ++mi)
#pragma unroll
    for (int ni = 0; ni < 2; ++ni)
#pragma unroll
      for (int r = 0; r < 4; ++r) {
        int lr = lBase + mi * 16 + (lane >> 4) * 4 + r;
        int p = pBase + ni * 16 + (lane & 15);
        float val = yd[mi][ni][r] + expf(acs_s[lr]) * yo[mi][ni][r];
        x_bf[(size_t)(tokBase + lr) * 4096 + h * 64 + p] = __float2bfloat16(val);
      }
}

// ---------------- launch ----------------
extern "C" void kernel_launch(void* const* d_in, const int* in_sizes, int n_in,
                              void* d_out, int out_size, void* d_ws, size_t ws_size,
                              hipStream_t stream) {
  const float* u       = (const float*)d_in[0];
  const float* W_in    = (const float*)d_in[1];
  const float* b_in    = (const float*)d_in[2];
  const float* W_out   = (const float*)d_in[3];
  const float* b_out   = (const float*)d_in[4];
  const float* A_log   = (const float*)d_in[5];
  const float* dt_bias = (const float*)d_in[6];

  float* y_out  = (float*)d_out;
  float* fs_out = y_out + (size_t)NTOK * MODEL_DIM;

  char* ws = (char*)d_ws;
  size_t off = 0;
  auto alloc = [&](size_t bytes) { char* p = ws + off; off += (bytes + 255) & ~255ull; return p; };
  bf16*  wout_bf = (bf16*) alloc((size_t)MODEL_DIM * INNER * 2);   // 16.8 MB
  bf16*  x_bf    = (bf16*) alloc((size_t)NTOK * INNER * 2);        // 67 MB (x, then y)
  bf16*  B_bf    = (bf16*) alloc((size_t)NTOK * STATE_DIM * 2);
  bf16*  C_bf    = (bf16*) alloc((size_t)NTOK * STATE_DIM * 2);
  float* dtraw   = (float*)alloc((size_t)NTOK * NHEADS * 4);
  float* dts     = (float*)alloc((size_t)NTOK * NHEADS * 4);
  float* a_dt    = (float*)alloc((size_t)NTOK * NHEADS * 4);
  float* acs     = (float*)alloc((size_t)BSZ * NCHUNK * NHEADS * 64 * 4);
  // region Q: states (bf16, 134 MB) aliased with {u_bf, win_bf} (dead after gemm_in)
  char*  Q       = alloc((size_t)BSZ * NCHUNK * NHEADS * 64 * 128 * 2);
  bf16*  states  = (bf16*)Q;
  bf16*  u_bf    = (bf16*)Q;
  bf16*  win_bf  = u_bf + (size_t)NTOK * MODEL_DIM;
  (void)ws_size; (void)off; (void)in_sizes; (void)n_in; (void)out_size;

  conv_f32_to_bf16<<<dim3(16384), dim3(256), 0, stream>>>(u, u_bf, NTOK * MODEL_DIM / 4);
  conv_win_pad<<<dim3(NPAD * MODEL_DIM / 1024), dim3(256), 0, stream>>>(W_in, win_bf);
  conv_f32_to_bf16<<<dim3(8192), dim3(256), 0, stream>>>(W_out, wout_bf, MODEL_DIM * INNER / 4);

  gemm_in256<<<dim3((NTOK / 256) * (NPAD / 192)), dim3(512), 0, stream>>>(
      u_bf, win_bf, b_in, x_bf, B_bf, C_bf, dtraw);

  prep_small<<<dim3(NTOK * NHEADS / 256), dim3(256), 0, stream>>>(dtraw, A_log, dt_bias, dts, a_dt);

  ssd_states_kernel<<<dim3(BSZ * NCHUNK * NHEADS), dim3(256), 0, stream>>>(
      x_bf, B_bf, dts, a_dt, acs, states);

  ssd_scan_kernel<<<dim3(BSZ * NHEADS * 4), dim3(256), 0, stream>>>(states, acs, fs_out);

  ssd_out_kernel<<<dim3(BSZ * NCHUNK * NHEADS), dim3(256), 0, stream>>>(
      x_bf, B_bf, C_bf, dts, acs, states);

  gemm_out256<<<dim3((MODEL_DIM / 256) * (NTOK / 256)), dim3(512), 0, stream>>>(
      x_bf, wout_bf, b_out, y_out);
}